// Round 13
// baseline (96.288 us; speedup 1.0000x reference)
//
#include <hip/hip_runtime.h>

typedef __bf16 bf16x8 __attribute__((ext_vector_type(8)));
typedef float f32x4 __attribute__((ext_vector_type(4)));
typedef unsigned short u16;

#define MFMA __builtin_amdgcn_mfma_f32_16x16x32_bf16

__device__ __forceinline__ u16 f2bf_bits(float f) {
  unsigned u = __builtin_bit_cast(unsigned, f);
  u = (u + 0x7fffu + ((u >> 16) & 1u)) >> 16;
  return (u16)u;
}
__device__ __forceinline__ __bf16 f2bf(float f) {
  u16 b = f2bf_bits(f);
  return __builtin_bit_cast(__bf16, b);
}
__device__ __forceinline__ float bf2f(u16 b) {
  return __builtin_bit_cast(float, (unsigned)b << 16);
}

// Barrier that drains ONLY LDS ops (lgkmcnt), leaving global loads (vmcnt) in
// flight across the barrier (T4 counted-wait pattern). Safe when the in-flight
// global loads are lane-private registers.
__device__ __forceinline__ void barrier_lds_only() {
  asm volatile("s_waitcnt lgkmcnt(0)" ::: "memory");
  __builtin_amdgcn_s_barrier();
}

// LDS tiles: logical [R][64] bf16 rows (128 B). XOR-swizzle 16B chunks with row
// to kill the 128B-stride bank conflict on ds_read_b128 (guide G4).
__device__ __forceinline__ int swz_off(int row, int col) {
  return row * 64 + ((((col >> 3) ^ row) & 7) << 3) + (col & 7);
}
__device__ __forceinline__ bf16x8 lds_read8(const __bf16* buf, int row, int col) {
  return *(const bf16x8*)(buf + (row * 64 + ((((col >> 3) ^ row) & 7) << 3)));
}
__device__ __forceinline__ void lds_write8(__bf16* buf, int row, int col, bf16x8 v) {
  *(bf16x8*)(buf + (row * 64 + ((((col >> 3) ^ row) & 7) << 3))) = v;
}

// ---------------- prep: Wt[192][1024] bf16 via coalesced LDS transpose.
__global__ __launch_bounds__(256) void prep_w_kernel(
    const float* __restrict__ Wq, const float* __restrict__ Wk,
    const float* __restrict__ Wv, u16* __restrict__ wtg) {
  __shared__ float tile[64][65];
  const int tid = threadIdx.x;
  const int kt = blockIdx.x & 15;  // 64 k-rows
  const int ct = blockIdx.x >> 4;  // 0=q, 1=k, 2=v
  const float* W = (ct == 0) ? Wq : ((ct == 1) ? Wk : Wv);
  const int k0 = kt * 64;
#pragma unroll
  for (int i = 0; i < 16; ++i) {
    int row = i * 4 + (tid >> 6), col = tid & 63;
    tile[row][col] = W[(size_t)(k0 + row) * 64 + col];
  }
  __syncthreads();
#pragma unroll
  for (int i = 0; i < 16; ++i) {
    int col = i * 4 + (tid >> 6), krow = tid & 63;
    wtg[(size_t)(ct * 64 + col) * 1024 + k0 + krow] = f2bf_bits(tile[krow][col]);
  }
}

// RoPE a (lo,hi) column pair via native v_sin/v_cos (revolutions + v_fract).
__device__ __forceinline__ void rope2(f32x4& lo, f32x4& hi, int i, float t_base) {
  float f = __expf(-(float)i * 0.28782313662425572f);  // 10000^(-i/32)
  const float inv2pi = 0.15915494309189535f;
#pragma unroll
  for (int r = 0; r < 4; ++r) {
    float rev = (t_base + (float)r) * f * inv2pi;
    rev = __builtin_amdgcn_fractf(rev);
    float sn = __builtin_amdgcn_sinf(rev);
    float cs = __builtin_amdgcn_cosf(rev);
    float L = lo[r], H = hi[r];
    lo[r] = L * cs - H * sn;
    hi[r] = H * cs + L * sn;
  }
}

// ---------------- fused QKV projection + RoPE (256 blocks x 64 rows).
// DEPTH-3 x prefetch + LDS-only barriers (R12). W depth-1. Wave map:
// 2 row-groups x 3 col-tiles; tile sets keep RoPE pairs (c,c+32) lane-local.
__global__ __launch_bounds__(512) void qkv_rope_kernel(
    const float* __restrict__ x, const u16* __restrict__ wtg,
    u16* __restrict__ qg, u16* __restrict__ kg, u16* __restrict__ vtg) {
  __shared__ __bf16 xbuf[2][64 * 64];
  __shared__ __bf16 wbuf[2][192 * 64];
  const int tid = threadIdx.x;
  const int w = tid >> 6, l = tid & 63;
  const int wrg = w & 1;
  const int wcg = w >> 1;
  const int lr = l & 15, lg = l >> 4;
  const int r0 = blockIdx.x * 64;
  const int b = r0 >> 11, t0 = r0 & 2047;
  constexpr int TM4[4][3] = {{0, 2, 8}, {1, 3, 9}, {4, 6, 10}, {5, 7, 11}};

  f32x4 acc[2][3];
#pragma unroll
  for (int rg = 0; rg < 2; ++rg)
#pragma unroll
    for (int j = 0; j < 3; ++j) acc[rg][j] = (f32x4){0.f, 0.f, 0.f, 0.f};

  const int srow = tid >> 3, sc8 = tid & 7;
  const float* xbase = x + (size_t)(r0 + srow) * 1024 + sc8 * 8;

  float4 xA0, xA1, xB0, xB1, xC0, xC1;
  bf16x8 swr[3];

  auto loadW = [&](int k0) {
#pragma unroll
    for (int s = 0; s < 3; ++s) {
      int id = tid + s * 512;
      swr[s] = *(const bf16x8*)(wtg + (size_t)(id >> 3) * 1024 + k0 + (id & 7) * 8);
    }
  };
  auto writeW = [&](int bsel) {
#pragma unroll
    for (int s = 0; s < 3; ++s) {
      int id = tid + s * 512;
      lds_write8(wbuf[bsel], id >> 3, (id & 7) * 8, swr[s]);
    }
  };
  auto loadX = [&](int step, int sel) {
    const float* p = xbase + (size_t)step * 64;
    if (sel == 0)      { xA0 = *(const float4*)p; xA1 = *(const float4*)(p + 4); }
    else if (sel == 1) { xB0 = *(const float4*)p; xB1 = *(const float4*)(p + 4); }
    else               { xC0 = *(const float4*)p; xC1 = *(const float4*)(p + 4); }
  };
  auto writeX = [&](int bsel, int sel) {
    float4 a0, a1;
    if (sel == 0)      { a0 = xA0; a1 = xA1; }
    else if (sel == 1) { a0 = xB0; a1 = xB1; }
    else               { a0 = xC0; a1 = xC1; }
    bf16x8 v;
    v[0] = f2bf(a0.x); v[1] = f2bf(a0.y); v[2] = f2bf(a0.z); v[3] = f2bf(a0.w);
    v[4] = f2bf(a1.x); v[5] = f2bf(a1.y); v[6] = f2bf(a1.z); v[7] = f2bf(a1.w);
    lds_write8(xbuf[bsel], srow, sc8 * 8, v);
  };

  loadX(0, 0);
  loadW(0);
  writeX(0, 0);
  writeW(0);
  loadX(1, 1);
  loadX(2, 2);
  barrier_lds_only();

#pragma unroll
  for (int s = 0; s < 16; ++s) {
    const int cur = s & 1;
    if (s < 13) loadX(s + 3, s % 3);
    if (s < 15) loadW((s + 1) * 64);
#pragma unroll
    for (int kk = 0; kk < 2; ++kk) {
      bf16x8 a0 = lds_read8(xbuf[cur], wrg * 32 + lr, kk * 32 + lg * 8);
      bf16x8 a1 = lds_read8(xbuf[cur], wrg * 32 + 16 + lr, kk * 32 + lg * 8);
#pragma unroll
      for (int j = 0; j < 3; ++j) {
        bf16x8 bb = lds_read8(wbuf[cur], TM4[wcg][j] * 16 + lr, kk * 32 + lg * 8);
        acc[0][j] = MFMA(a0, bb, acc[0][j], 0, 0, 0);
        acc[1][j] = MFMA(a1, bb, acc[1][j], 0, 0, 0);
      }
    }
    if (s < 15) {
      writeX(cur ^ 1, (s + 1) % 3);
      writeW(cur ^ 1);
      barrier_lds_only();
    }
  }

  const int ph = (wcg & 1) * 16 + lr;
#pragma unroll
  for (int rg = 0; rg < 2; ++rg) {
    const int rowb = wrg * 32 + rg * 16 + lg * 4;
    const float t_base = (float)(t0 + rowb);
    rope2(acc[rg][0], acc[rg][1], ph, t_base);
    if (wcg < 2) {
#pragma unroll
      for (int r = 0; r < 4; ++r) {
        size_t rowo = (size_t)(r0 + rowb + r) * 64;
        qg[rowo + ph] = f2bf_bits(acc[rg][0][r] * 0.03125f);
        qg[rowo + 32 + ph] = f2bf_bits(acc[rg][1][r] * 0.03125f);
      }
    } else {
#pragma unroll
      for (int r = 0; r < 4; ++r) {
        size_t rowo = (size_t)(r0 + rowb + r) * 64;
        kg[rowo + ph] = f2bf_bits(acc[rg][0][r]);
        kg[rowo + 32 + ph] = f2bf_bits(acc[rg][1][r]);
      }
    }
    {
      const int d = (TM4[wcg][2] - 8) * 16 + lr;
      ushort4 uv;
      uv.x = f2bf_bits(acc[rg][2][0]);
      uv.y = f2bf_bits(acc[rg][2][1]);
      uv.z = f2bf_bits(acc[rg][2][2]);
      uv.w = f2bf_bits(acc[rg][2][3]);
      *(ushort4*)(vtg + (size_t)(b * 64 + d) * 2048 + t0 + rowb) = uv;
    }
  }
}

// ---------------- flash attention split-KV partials — NO K/V LDS staging.
// Per iter a block touches one 8KB K tile + one 8KB V tile; the x4 intra-block
// wave reuse is served by L1 (32KB/CU), so LDS staging was pure overhead
// (guide common-mistake #7). Direct global fragment reads (same indices, 16B/
// lane) delete the double-buffer, the staging code, and EVERY barrier in the
// main loop — waves free-run; LDS 41KB -> 8KB raises co-residency 3 -> ~8
// blocks/CU. P round-trip stays in per-wave LDS (wave-internal, no barrier).
// Fixed-shift softmax P = exp(S-8). NO cross-block fences (R4: ~400us).
__global__ __launch_bounds__(256) void attn_part_kernel(
    const u16* __restrict__ qg, const u16* __restrict__ kg,
    const u16* __restrict__ vtg, u16* __restrict__ opart,
    float* __restrict__ lpart, float* __restrict__ out, int CT, int NCH) {
  const int idx = blockIdx.x;
  const int b = idx / (32 * NCH);
  const int rem = idx % (32 * NCH);
  const int qt = rem / NCH, ch = rem % NCH;
  const int t0v = ch * CT;
  if (t0v > qt) return;
  const int t1v = min(qt + 1, t0v + CT);
  const int nv = qt / CT + 1;

  __shared__ __bf16 pbuf[4 * 16 * 64];
  const int tid = threadIdx.x;
  const int w = tid >> 6, l = tid & 63;
  const int lr = l & 15, lg = l >> 4;
  const int q0 = qt * 64;
  const float NEG_INF = -__builtin_inff();

  const u16* qrow = qg + (size_t)(b * 2048 + q0 + w * 16 + lr) * 64;
  bf16x8 qf0 = *(const bf16x8*)(qrow + lg * 8);
  bf16x8 qf1 = *(const bf16x8*)(qrow + 32 + lg * 8);

  const u16* kgb = kg + (size_t)(b * 2048) * 64;
  const u16* vtb = vtg + (size_t)(b * 64) * 2048;

  f32x4 acc_o[4];
#pragma unroll
  for (int n = 0; n < 4; ++n) acc_o[n] = (f32x4){0.f, 0.f, 0.f, 0.f};
  float l_p[4] = {0.f, 0.f, 0.f, 0.f};

  for (int c = t0v; c < t1v; ++c) {
    const u16* ktile = kgb + (size_t)c * 64 * 64;

    f32x4 s4[4];
#pragma unroll
    for (int nt = 0; nt < 4; ++nt) {
      const u16* krow = ktile + (size_t)(nt * 16 + lr) * 64;
      bf16x8 k0 = *(const bf16x8*)(krow + lg * 8);
      bf16x8 k1 = *(const bf16x8*)(krow + 32 + lg * 8);
      f32x4 t = (f32x4){0.f, 0.f, 0.f, 0.f};
      t = MFMA(qf0, k0, t, 0, 0, 0);
      t = MFMA(qf1, k1, t, 0, 0, 0);
      s4[nt] = t;
    }
    if (c == qt) {  // causal mask on diagonal tile
#pragma unroll
      for (int nt = 0; nt < 4; ++nt)
#pragma unroll
        for (int r = 0; r < 4; ++r) {
          int kv = nt * 16 + lr, qq = w * 16 + lg * 4 + r;
          if (kv > qq) s4[nt][r] = NEG_INF;
        }
    }
    // P = exp(S - 8); accumulate per-lane row sums (reduced once after loop)
    __bf16* pw = pbuf + w * (16 * 64);
#pragma unroll
    for (int nt = 0; nt < 4; ++nt)
#pragma unroll
      for (int r = 0; r < 4; ++r) {
        float p = __expf(s4[nt][r] - 8.0f);
        l_p[r] += p;
        pw[swz_off(lg * 4 + r, nt * 16 + lr)] = f2bf(p);
      }
    // wave-internal LDS is in-order: no barrier between P write and read
#pragma unroll
    for (int h = 0; h < 2; ++h) {
      bf16x8 pf = lds_read8(pw, lr, h * 32 + lg * 8);
#pragma unroll
      for (int nt = 0; nt < 4; ++nt) {
        bf16x8 vf = *(const bf16x8*)(vtb + (size_t)(nt * 16 + lr) * 2048 +
                                     c * 64 + h * 32 + lg * 8);
        acc_o[nt] = MFMA(pf, vf, acc_o[nt], 0, 0, 0);
      }
    }
    // no barrier: no shared K/V state; pbuf is per-wave
  }

  // row sums: reduce l_p across the 16 lr lanes (masks 1,2,4,8 stay in group)
  float lsum[4];
#pragma unroll
  for (int r = 0; r < 4; ++r) {
    float s = l_p[r];
    s += __shfl_xor(s, 1);
    s += __shfl_xor(s, 2);
    s += __shfl_xor(s, 4);
    s += __shfl_xor(s, 8);
    lsum[r] = s;
  }

  if (nv == 1) {  // single chunk: normalize and write out directly
#pragma unroll
    for (int r = 0; r < 4; ++r) {
      float inv = 1.0f / lsum[r];
      size_t rowo = (size_t)(b * 2048 + q0 + w * 16 + lg * 4 + r) * 64;
#pragma unroll
      for (int nt = 0; nt < 4; ++nt)
        out[rowo + nt * 16 + lr] = acc_o[nt][r] * inv;
    }
    return;
  }

  // write unnormalized partial (bf16) + row sums (kernel boundary = coherence)
  const size_t slot = (size_t)(b * 32 + qt) * NCH + ch;
  u16* oslot = opart + slot * 4096;
#pragma unroll
  for (int r = 0; r < 4; ++r) {
    int row = w * 16 + lg * 4 + r;
#pragma unroll
    for (int nt = 0; nt < 4; ++nt)
      oslot[row * 64 + nt * 16 + lr] = f2bf_bits(acc_o[nt][r]);
    if (lr == 0) lpart[slot * 64 + row] = lsum[r];
  }
}

// ---------------- combine partials (unweighted ordered sum; same shift in all
// chunks so weights==1): out = sum_c O'_c / sum_c l_c.
__global__ __launch_bounds__(256) void attn_combine_kernel(
    const u16* __restrict__ opart, const float* __restrict__ lpart,
    float* __restrict__ out, int CT, int NCH) {
  const int bq = blockIdx.x >> 2;
  const int quarter = blockIdx.x & 3;
  const int b = bq >> 5, qt = bq & 31;
  const int nv = qt / CT + 1;
  if (nv == 1) return;  // written directly by attn_part
  const int row = quarter * 16 + (threadIdx.x >> 4);
  const int col = (threadIdx.x & 15) * 4;
  const size_t slot0 = (size_t)(b * 32 + qt) * NCH;

  float denom = 0.f;
  float acc[4] = {0.f, 0.f, 0.f, 0.f};
  for (int c = 0; c < nv; ++c) {
    denom += lpart[(slot0 + c) * 64 + row];
    ushort4 pv = *(const ushort4*)(opart + (slot0 + c) * 4096 + row * 64 + col);
    acc[0] += bf2f(pv.x);
    acc[1] += bf2f(pv.y);
    acc[2] += bf2f(pv.z);
    acc[3] += bf2f(pv.w);
  }
  float inv = 1.0f / denom;
  float4 o;
  o.x = acc[0] * inv; o.y = acc[1] * inv; o.z = acc[2] * inv; o.w = acc[3] * inv;
  *(float4*)(out + ((size_t)(b * 2048 + qt * 64 + row)) * 64 + col) = o;
}

extern "C" void kernel_launch(void* const* d_in, const int* in_sizes, int n_in,
                              void* d_out, int out_size, void* d_ws, size_t ws_size,
                              hipStream_t stream) {
  const float* x = (const float*)d_in[0];
  const float* Wq = (const float*)d_in[1];
  const float* Wk = (const float*)d_in[2];
  const float* Wv = (const float*)d_in[3];
  float* out = (float*)d_out;
  char* ws = (char*)d_ws;
  // ws layout: Wt | q | k | vt | Opart | lpart
  u16* wtg = (u16*)ws;                                  // 393216 B
  u16* qg = (u16*)(ws + 393216);                        // 2 MB
  u16* kg = (u16*)(ws + 393216 + 2097152);              // 2 MB
  u16* vtg = (u16*)(ws + 393216 + 2u * 2097152);        // 2 MB
  const size_t base = 393216 + 3u * 2097152;            // 6,684,672 B
  int NCH = 8;  // proven optimum (R11: NCH=16 +5us; R1: no-split +35us)
  // per slot: 8192 B O' + 256 B l
  while (NCH > 1 && base + (size_t)256 * NCH * 8448 > ws_size) NCH >>= 1;
  const int CT = 32 / NCH;
  u16* opart = (u16*)(ws + base);
  float* lpart = (float*)(ws + base + (size_t)256 * NCH * 8192);

  prep_w_kernel<<<dim3(48), dim3(256), 0, stream>>>(Wq, Wk, Wv, wtg);
  qkv_rope_kernel<<<dim3(256), dim3(512), 0, stream>>>(x, wtg, qg, kg, vtg);
  attn_part_kernel<<<dim3(8 * 32 * NCH), dim3(256), 0, stream>>>(
      qg, kg, vtg, opart, lpart, out, CT, NCH);
  attn_combine_kernel<<<dim3(256 * 4), dim3(256), 0, stream>>>(opart, lpart, out, CT, NCH);
}

// Round 14
// 57.291 us; speedup vs baseline: 1.6807x; 1.6807x over previous
//
#include <hip/hip_runtime.h>

typedef __bf16 bf16x8 __attribute__((ext_vector_type(8)));
typedef float f32x4 __attribute__((ext_vector_type(4)));
typedef unsigned short u16;

#define MFMA __builtin_amdgcn_mfma_f32_16x16x32_bf16

__device__ __forceinline__ u16 f2bf_bits(float f) {
  unsigned u = __builtin_bit_cast(unsigned, f);
  u = (u + 0x7fffu + ((u >> 16) & 1u)) >> 16;
  return (u16)u;
}
__device__ __forceinline__ __bf16 f2bf(float f) {
  u16 b = f2bf_bits(f);
  return __builtin_bit_cast(__bf16, b);
}
__device__ __forceinline__ float bf2f(u16 b) {
  return __builtin_bit_cast(float, (unsigned)b << 16);
}

// Async global->LDS, 16B per lane. HW dest = wave-uniform LDS base + lane*16
// (guide §5); source address is per-lane, so the XOR swizzle moves to the
// GLOBAL address (rule #21: linear dest + inverse-swz source + swz read).
__device__ __forceinline__ void gload_lds16(const u16* g, __bf16* lds) {
  __builtin_amdgcn_global_load_lds(
      (const __attribute__((address_space(1))) void*)g,
      (__attribute__((address_space(3))) void*)lds, 16, 0, 0);
}

// LDS tiles: logical [R][64] bf16 rows (128 B). XOR-swizzle 16B chunks with row
// to kill the 128B-stride bank conflict on ds_read_b128 (guide G4).
__device__ __forceinline__ int swz_off(int row, int col) {
  return row * 64 + ((((col >> 3) ^ row) & 7) << 3) + (col & 7);
}
__device__ __forceinline__ bf16x8 lds_read8(const __bf16* buf, int row, int col) {
  return *(const bf16x8*)(buf + (row * 64 + ((((col >> 3) ^ row) & 7) << 3)));
}
__device__ __forceinline__ void lds_write8(__bf16* buf, int row, int col, bf16x8 v) {
  *(bf16x8*)(buf + (row * 64 + ((((col >> 3) ^ row) & 7) << 3))) = v;
}

// ---------------- prep: Wt[192][1024] bf16 via coalesced LDS transpose.
__global__ __launch_bounds__(256) void prep_w_kernel(
    const float* __restrict__ Wq, const float* __restrict__ Wk,
    const float* __restrict__ Wv, u16* __restrict__ wtg) {
  __shared__ float tile[64][65];
  const int tid = threadIdx.x;
  const int kt = blockIdx.x & 15;  // 64 k-rows
  const int ct = blockIdx.x >> 4;  // 0=q, 1=k, 2=v
  const float* W = (ct == 0) ? Wq : ((ct == 1) ? Wk : Wv);
  const int k0 = kt * 64;
#pragma unroll
  for (int i = 0; i < 16; ++i) {
    int row = i * 4 + (tid >> 6), col = tid & 63;
    tile[row][col] = W[(size_t)(k0 + row) * 64 + col];
  }
  __syncthreads();
#pragma unroll
  for (int i = 0; i < 16; ++i) {
    int col = i * 4 + (tid >> 6), krow = tid & 63;
    wtg[(size_t)(ct * 64 + col) * 1024 + k0 + krow] = f2bf_bits(tile[krow][col]);
  }
}

// RoPE a (lo,hi) column pair via native v_sin/v_cos (revolutions + v_fract).
__device__ __forceinline__ void rope2(f32x4& lo, f32x4& hi, int i, float t_base) {
  float f = __expf(-(float)i * 0.28782313662425572f);  // 10000^(-i/32)
  const float inv2pi = 0.15915494309189535f;
#pragma unroll
  for (int r = 0; r < 4; ++r) {
    float rev = (t_base + (float)r) * f * inv2pi;
    rev = __builtin_amdgcn_fractf(rev);
    float sn = __builtin_amdgcn_sinf(rev);
    float cs = __builtin_amdgcn_cosf(rev);
    float L = lo[r], H = hi[r];
    lo[r] = L * cs - H * sn;
    hi[r] = H * cs + L * sn;
  }
}

// ---------------- fused QKV projection + RoPE (256 blocks x 64 rows).
// W staging via global_load_lds (no VGPR round-trip, no ds_write): per-lane
// global addr carries the inverse XOR so the linear lane*16 LDS writes land in
// the swizzled layout the reads expect. Counted-vmcnt barriers (T4): vmcnt(2)
// guarantees the W gl_lds batch (issued a full step earlier, older in the
// FIFO) completed while the two newest x prefetch loads stay in flight.
// DEPTH-3 x prefetch (reg-staged: needs fp32->bf16 convert). Wave map:
// 2 row-groups x 3 col-tiles; tile sets keep RoPE pairs (c,c+32) lane-local.
__global__ __launch_bounds__(512) void qkv_rope_kernel(
    const float* __restrict__ x, const u16* __restrict__ wtg,
    u16* __restrict__ qg, u16* __restrict__ kg, u16* __restrict__ vtg) {
  __shared__ __bf16 xbuf[2][64 * 64];
  __shared__ __bf16 wbuf[2][192 * 64];
  const int tid = threadIdx.x;
  const int w = tid >> 6, l = tid & 63;
  const int wrg = w & 1;
  const int wcg = w >> 1;
  const int lr = l & 15, lg = l >> 4;
  const int r0 = blockIdx.x * 64;
  const int b = r0 >> 11, t0 = r0 & 2047;
  constexpr int TM4[4][3] = {{0, 2, 8}, {1, 3, 9}, {4, 6, 10}, {5, 7, 11}};

  f32x4 acc[2][3];
#pragma unroll
  for (int rg = 0; rg < 2; ++rg)
#pragma unroll
    for (int j = 0; j < 3; ++j) acc[rg][j] = (f32x4){0.f, 0.f, 0.f, 0.f};

  const int srow = tid >> 3, sc8 = tid & 7;
  const float* xbase = x + (size_t)(r0 + srow) * 1024 + sc8 * 8;

  float4 xA0, xA1, xB0, xB1, xC0, xC1;

  auto glW = [&](int k0, int bsel) {  // 3 x global_load_lds, pre-swz source
#pragma unroll
    for (int s2 = 0; s2 < 3; ++s2) {
      int id = tid + s2 * 512;
      int row = id >> 3, p = id & 7;
      const u16* src = wtg + (size_t)row * 1024 + k0 + (((p ^ row) & 7) << 3);
      __bf16* dst = wbuf[bsel] + ((size_t)((tid >> 6) * 64 + s2 * 512)) * 8;
      gload_lds16(src, dst);
    }
  };
  auto loadX = [&](int step, int sel) {
    const float* p = xbase + (size_t)step * 64;
    if (sel == 0)      { xA0 = *(const float4*)p; xA1 = *(const float4*)(p + 4); }
    else if (sel == 1) { xB0 = *(const float4*)p; xB1 = *(const float4*)(p + 4); }
    else               { xC0 = *(const float4*)p; xC1 = *(const float4*)(p + 4); }
  };
  auto writeX = [&](int bsel, int sel) {
    float4 a0, a1;
    if (sel == 0)      { a0 = xA0; a1 = xA1; }
    else if (sel == 1) { a0 = xB0; a1 = xB1; }
    else               { a0 = xC0; a1 = xC1; }
    bf16x8 v;
    v[0] = f2bf(a0.x); v[1] = f2bf(a0.y); v[2] = f2bf(a0.z); v[3] = f2bf(a0.w);
    v[4] = f2bf(a1.x); v[5] = f2bf(a1.y); v[6] = f2bf(a1.z); v[7] = f2bf(a1.w);
    lds_write8(xbuf[bsel], srow, sc8 * 8, v);
  };

  // prologue: x(0)->LDS0, W(0) gl_lds->LDS0; x(1),x(2) left in flight
  loadX(0, 0);
  glW(0, 0);
  writeX(0, 0);
  loadX(1, 1);
  loadX(2, 2);
  asm volatile("s_waitcnt vmcnt(4) lgkmcnt(0)" ::: "memory");  // W(0) done; x(1,2) fly
  __builtin_amdgcn_s_barrier();

#pragma unroll
  for (int s = 0; s < 16; ++s) {
    const int cur = s & 1;
    if (s < 15) glW((s + 1) * 64, cur ^ 1);  // issued a full step before use
    if (s < 13) loadX(s + 3, s % 3);
#pragma unroll
    for (int kk = 0; kk < 2; ++kk) {
      bf16x8 a0 = lds_read8(xbuf[cur], wrg * 32 + lr, kk * 32 + lg * 8);
      bf16x8 a1 = lds_read8(xbuf[cur], wrg * 32 + 16 + lr, kk * 32 + lg * 8);
#pragma unroll
      for (int j = 0; j < 3; ++j) {
        bf16x8 bb = lds_read8(wbuf[cur], TM4[wcg][j] * 16 + lr, kk * 32 + lg * 8);
        acc[0][j] = MFMA(a0, bb, acc[0][j], 0, 0, 0);
        acc[1][j] = MFMA(a1, bb, acc[1][j], 0, 0, 0);
      }
    }
    if (s < 15) {
      writeX(cur ^ 1, (s + 1) % 3);
      if (s < 13) {
        // FIFO: x(s+2)^2 , W(s+1)^3 , x(s+3)^2 -> vmcnt(2) completes W,
        // keeps the newest x pair in flight across the barrier.
        asm volatile("s_waitcnt vmcnt(2) lgkmcnt(0)" ::: "memory");
      } else {
        asm volatile("s_waitcnt vmcnt(0) lgkmcnt(0)" ::: "memory");
      }
      __builtin_amdgcn_s_barrier();
    }
  }

  const int ph = (wcg & 1) * 16 + lr;
#pragma unroll
  for (int rg = 0; rg < 2; ++rg) {
    const int rowb = wrg * 32 + rg * 16 + lg * 4;
    const float t_base = (float)(t0 + rowb);
    rope2(acc[rg][0], acc[rg][1], ph, t_base);
    if (wcg < 2) {
#pragma unroll
      for (int r = 0; r < 4; ++r) {
        size_t rowo = (size_t)(r0 + rowb + r) * 64;
        qg[rowo + ph] = f2bf_bits(acc[rg][0][r] * 0.03125f);
        qg[rowo + 32 + ph] = f2bf_bits(acc[rg][1][r] * 0.03125f);
      }
    } else {
#pragma unroll
      for (int r = 0; r < 4; ++r) {
        size_t rowo = (size_t)(r0 + rowb + r) * 64;
        kg[rowo + ph] = f2bf_bits(acc[rg][0][r]);
        kg[rowo + 32 + ph] = f2bf_bits(acc[rg][1][r]);
      }
    }
    {
      const int d = (TM4[wcg][2] - 8) * 16 + lr;
      ushort4 uv;
      uv.x = f2bf_bits(acc[rg][2][0]);
      uv.y = f2bf_bits(acc[rg][2][1]);
      uv.z = f2bf_bits(acc[rg][2][2]);
      uv.w = f2bf_bits(acc[rg][2][3]);
      *(ushort4*)(vtg + (size_t)(b * 64 + d) * 2048 + t0 + rowb) = uv;
    }
  }
}

// ---------------- flash attention split-KV partials: K/V staging via
// global_load_lds (pre-swz source, linear LDS dest), double-buffered,
// issued one full iteration ahead; gl_lds is the ONLY VMEM in the loop so
// the barrier's vmcnt(0) = "staging done", with a whole iter of cover.
// (R13 proved unstaged direct reads lose 20us: coalescing + latency.)
// Fixed-shift softmax P = exp(S-8). NO cross-block fences (R4: ~400us).
__global__ __launch_bounds__(256) void attn_part_kernel(
    const u16* __restrict__ qg, const u16* __restrict__ kg,
    const u16* __restrict__ vtg, u16* __restrict__ opart,
    float* __restrict__ lpart, float* __restrict__ out, int CT, int NCH) {
  const int idx = blockIdx.x;
  const int b = idx / (32 * NCH);
  const int rem = idx % (32 * NCH);
  const int qt = rem / NCH, ch = rem % NCH;
  const int t0v = ch * CT;
  if (t0v > qt) return;  // uniform early-exit (before any barrier)
  const int t1v = min(qt + 1, t0v + CT);
  const int nv = qt / CT + 1;

  __shared__ __bf16 kbuf[2][64 * 64];
  __shared__ __bf16 vbuf[2][64 * 64];
  __shared__ __bf16 pbuf[4 * 16 * 64];
  const int tid = threadIdx.x;
  const int w = tid >> 6, l = tid & 63;
  const int lr = l & 15, lg = l >> 4;
  const int q0 = qt * 64;
  const float NEG_INF = -__builtin_inff();

  const u16* qrow = qg + (size_t)(b * 2048 + q0 + w * 16 + lr) * 64;
  bf16x8 qf0 = *(const bf16x8*)(qrow + lg * 8);
  bf16x8 qf1 = *(const bf16x8*)(qrow + 32 + lg * 8);

  const u16* kgb = kg + (size_t)(b * 2048) * 64;
  const u16* vtb = vtg + (size_t)(b * 64) * 2048;

  auto glKV = [&](int c, int bsel) {  // 4 x global_load_lds per thread
#pragma unroll
    for (int s2 = 0; s2 < 2; ++s2) {
      int id = tid + s2 * 256;
      int row = id >> 3, p = id & 7;
      int c8 = (p ^ row) & 7;
      const u16* ksrc = kgb + (size_t)(c * 64 + row) * 64 + (c8 << 3);
      const u16* vsrc = vtb + (size_t)row * 2048 + c * 64 + (c8 << 3);
      __bf16* kdst = kbuf[bsel] + ((size_t)((tid >> 6) * 64 + s2 * 256)) * 8;
      __bf16* vdst = vbuf[bsel] + ((size_t)((tid >> 6) * 64 + s2 * 256)) * 8;
      gload_lds16(ksrc, kdst);
      gload_lds16(vsrc, vdst);
    }
  };

  f32x4 acc_o[4];
#pragma unroll
  for (int n = 0; n < 4; ++n) acc_o[n] = (f32x4){0.f, 0.f, 0.f, 0.f};
  float l_p[4] = {0.f, 0.f, 0.f, 0.f};

  glKV(t0v, 0);
  asm volatile("s_waitcnt vmcnt(0) lgkmcnt(0)" ::: "memory");
  __builtin_amdgcn_s_barrier();

  for (int c = t0v; c < t1v; ++c) {
    const int cur = (c - t0v) & 1;
    const bool more = (c + 1 < t1v);
    if (more) glKV(c + 1, cur ^ 1);  // full iteration of latency cover

    f32x4 s4[4];
#pragma unroll
    for (int nt = 0; nt < 4; ++nt) {
      bf16x8 k0 = lds_read8(kbuf[cur], nt * 16 + lr, lg * 8);
      bf16x8 k1 = lds_read8(kbuf[cur], nt * 16 + lr, 32 + lg * 8);
      f32x4 t = (f32x4){0.f, 0.f, 0.f, 0.f};
      t = MFMA(qf0, k0, t, 0, 0, 0);
      t = MFMA(qf1, k1, t, 0, 0, 0);
      s4[nt] = t;
    }
    if (c == qt) {  // causal mask on diagonal tile
#pragma unroll
      for (int nt = 0; nt < 4; ++nt)
#pragma unroll
        for (int r = 0; r < 4; ++r) {
          int kv = nt * 16 + lr, qq = w * 16 + lg * 4 + r;
          if (kv > qq) s4[nt][r] = NEG_INF;
        }
    }
    // P = exp(S - 8); accumulate per-lane row sums (reduced once after loop)
    __bf16* pw = pbuf + w * (16 * 64);
#pragma unroll
    for (int nt = 0; nt < 4; ++nt)
#pragma unroll
      for (int r = 0; r < 4; ++r) {
        float p = __expf(s4[nt][r] - 8.0f);
        l_p[r] += p;
        pw[swz_off(lg * 4 + r, nt * 16 + lr)] = f2bf(p);
      }
    // wave-internal LDS is in-order: no barrier between P write and read
#pragma unroll
    for (int h = 0; h < 2; ++h) {
      bf16x8 pf = lds_read8(pw, lr, h * 32 + lg * 8);
#pragma unroll
      for (int nt = 0; nt < 4; ++nt) {
        bf16x8 vf = lds_read8(vbuf[cur], nt * 16 + lr, h * 32 + lg * 8);
        acc_o[nt] = MFMA(pf, vf, acc_o[nt], 0, 0, 0);
      }
    }
    if (more) {
      asm volatile("s_waitcnt vmcnt(0) lgkmcnt(0)" ::: "memory");  // staging done
      __builtin_amdgcn_s_barrier();
    }
  }

  // row sums: reduce l_p across the 16 lr lanes (masks 1,2,4,8 stay in group)
  float lsum[4];
#pragma unroll
  for (int r = 0; r < 4; ++r) {
    float s = l_p[r];
    s += __shfl_xor(s, 1);
    s += __shfl_xor(s, 2);
    s += __shfl_xor(s, 4);
    s += __shfl_xor(s, 8);
    lsum[r] = s;
  }

  if (nv == 1) {  // single chunk: normalize and write out directly
#pragma unroll
    for (int r = 0; r < 4; ++r) {
      float inv = 1.0f / lsum[r];
      size_t rowo = (size_t)(b * 2048 + q0 + w * 16 + lg * 4 + r) * 64;
#pragma unroll
      for (int nt = 0; nt < 4; ++nt)
        out[rowo + nt * 16 + lr] = acc_o[nt][r] * inv;
    }
    return;
  }

  // write unnormalized partial (bf16) + row sums (kernel boundary = coherence)
  const size_t slot = (size_t)(b * 32 + qt) * NCH + ch;
  u16* oslot = opart + slot * 4096;
#pragma unroll
  for (int r = 0; r < 4; ++r) {
    int row = w * 16 + lg * 4 + r;
#pragma unroll
    for (int nt = 0; nt < 4; ++nt)
      oslot[row * 64 + nt * 16 + lr] = f2bf_bits(acc_o[nt][r]);
    if (lr == 0) lpart[slot * 64 + row] = lsum[r];
  }
}

// ---------------- combine partials (unweighted ordered sum; same shift in all
// chunks so weights==1): out = sum_c O'_c / sum_c l_c.
__global__ __launch_bounds__(256) void attn_combine_kernel(
    const u16* __restrict__ opart, const float* __restrict__ lpart,
    float* __restrict__ out, int CT, int NCH) {
  const int bq = blockIdx.x >> 2;
  const int quarter = blockIdx.x & 3;
  const int b = bq >> 5, qt = bq & 31;
  const int nv = qt / CT + 1;
  if (nv == 1) return;  // written directly by attn_part
  const int row = quarter * 16 + (threadIdx.x >> 4);
  const int col = (threadIdx.x & 15) * 4;
  const size_t slot0 = (size_t)(b * 32 + qt) * NCH;

  float denom = 0.f;
  float acc[4] = {0.f, 0.f, 0.f, 0.f};
  for (int c = 0; c < nv; ++c) {
    denom += lpart[(slot0 + c) * 64 + row];
    ushort4 pv = *(const ushort4*)(opart + (slot0 + c) * 4096 + row * 64 + col);
    acc[0] += bf2f(pv.x);
    acc[1] += bf2f(pv.y);
    acc[2] += bf2f(pv.z);
    acc[3] += bf2f(pv.w);
  }
  float inv = 1.0f / denom;
  float4 o;
  o.x = acc[0] * inv; o.y = acc[1] * inv; o.z = acc[2] * inv; o.w = acc[3] * inv;
  *(float4*)(out + ((size_t)(b * 2048 + qt * 64 + row)) * 64 + col) = o;
}

extern "C" void kernel_launch(void* const* d_in, const int* in_sizes, int n_in,
                              void* d_out, int out_size, void* d_ws, size_t ws_size,
                              hipStream_t stream) {
  const float* x = (const float*)d_in[0];
  const float* Wq = (const float*)d_in[1];
  const float* Wk = (const float*)d_in[2];
  const float* Wv = (const float*)d_in[3];
  float* out = (float*)d_out;
  char* ws = (char*)d_ws;
  // ws layout: Wt | q | k | vt | Opart | lpart
  u16* wtg = (u16*)ws;                                  // 393216 B
  u16* qg = (u16*)(ws + 393216);                        // 2 MB
  u16* kg = (u16*)(ws + 393216 + 2097152);              // 2 MB
  u16* vtg = (u16*)(ws + 393216 + 2u * 2097152);        // 2 MB
  const size_t base = 393216 + 3u * 2097152;            // 6,684,672 B
  int NCH = 8;  // proven optimum (R11: NCH=16 +5us; R1: no-split +35us)
  // per slot: 8192 B O' + 256 B l
  while (NCH > 1 && base + (size_t)256 * NCH * 8448 > ws_size) NCH >>= 1;
  const int CT = 32 / NCH;
  u16* opart = (u16*)(ws + base);
  float* lpart = (float*)(ws + base + (size_t)256 * NCH * 8192);

  prep_w_kernel<<<dim3(48), dim3(256), 0, stream>>>(Wq, Wk, Wv, wtg);
  qkv_rope_kernel<<<dim3(256), dim3(512), 0, stream>>>(x, wtg, qg, kg, vtg);
  attn_part_kernel<<<dim3(8 * 32 * NCH), dim3(256), 0, stream>>>(
      qg, kg, vtg, opart, lpart, out, CT, NCH);
  attn_combine_kernel<<<dim3(256 * 4), dim3(256), 0, stream>>>(opart, lpart, out, CT, NCH);
}

// Round 15
// 55.443 us; speedup vs baseline: 1.7367x; 1.0333x over previous
//
#include <hip/hip_runtime.h>

typedef __bf16 bf16x8 __attribute__((ext_vector_type(8)));
typedef float f32x4 __attribute__((ext_vector_type(4)));
typedef unsigned short u16;

#define MFMA __builtin_amdgcn_mfma_f32_16x16x32_bf16

__device__ __forceinline__ u16 f2bf_bits(float f) {
  unsigned u = __builtin_bit_cast(unsigned, f);
  u = (u + 0x7fffu + ((u >> 16) & 1u)) >> 16;
  return (u16)u;
}
__device__ __forceinline__ __bf16 f2bf(float f) {
  u16 b = f2bf_bits(f);
  return __builtin_bit_cast(__bf16, b);
}
__device__ __forceinline__ float bf2f(u16 b) {
  return __builtin_bit_cast(float, (unsigned)b << 16);
}

// Barrier that drains ONLY LDS ops (lgkmcnt), leaving global loads (vmcnt) in
// flight across the barrier (T4). Safe when in-flight loads are lane-private.
__device__ __forceinline__ void barrier_lds_only() {
  asm volatile("s_waitcnt lgkmcnt(0)" ::: "memory");
  __builtin_amdgcn_s_barrier();
}

// LDS tiles: logical [R][64] bf16 rows (128 B). XOR-swizzle 16B chunks with row
// to kill the 128B-stride bank conflict on ds_read_b128 (guide G4).
__device__ __forceinline__ int swz_off(int row, int col) {
  return row * 64 + ((((col >> 3) ^ row) & 7) << 3) + (col & 7);
}
__device__ __forceinline__ bf16x8 lds_read8(const __bf16* buf, int row, int col) {
  return *(const bf16x8*)(buf + (row * 64 + ((((col >> 3) ^ row) & 7) << 3)));
}
__device__ __forceinline__ void lds_write8(__bf16* buf, int row, int col, bf16x8 v) {
  *(bf16x8*)(buf + (row * 64 + ((((col >> 3) ^ row) & 7) << 3))) = v;
}

// ---------------- prep: Wt[192][1024] bf16 via coalesced LDS transpose.
__global__ __launch_bounds__(256) void prep_w_kernel(
    const float* __restrict__ Wq, const float* __restrict__ Wk,
    const float* __restrict__ Wv, u16* __restrict__ wtg) {
  __shared__ float tile[64][65];
  const int tid = threadIdx.x;
  const int kt = blockIdx.x & 15;  // 64 k-rows
  const int ct = blockIdx.x >> 4;  // 0=q, 1=k, 2=v
  const float* W = (ct == 0) ? Wq : ((ct == 1) ? Wk : Wv);
  const int k0 = kt * 64;
#pragma unroll
  for (int i = 0; i < 16; ++i) {
    int row = i * 4 + (tid >> 6), col = tid & 63;
    tile[row][col] = W[(size_t)(k0 + row) * 64 + col];
  }
  __syncthreads();
#pragma unroll
  for (int i = 0; i < 16; ++i) {
    int col = i * 4 + (tid >> 6), krow = tid & 63;
    wtg[(size_t)(ct * 64 + col) * 1024 + k0 + krow] = f2bf_bits(tile[krow][col]);
  }
}

// RoPE a (lo,hi) column pair via native v_sin/v_cos (revolutions + v_fract).
__device__ __forceinline__ void rope2(f32x4& lo, f32x4& hi, int i, float t_base) {
  float f = __expf(-(float)i * 0.28782313662425572f);  // 10000^(-i/32)
  const float inv2pi = 0.15915494309189535f;
#pragma unroll
  for (int r = 0; r < 4; ++r) {
    float rev = (t_base + (float)r) * f * inv2pi;
    rev = __builtin_amdgcn_fractf(rev);
    float sn = __builtin_amdgcn_sinf(rev);
    float cs = __builtin_amdgcn_cosf(rev);
    float L = lo[r], H = hi[r];
    lo[r] = L * cs - H * sn;
    hi[r] = H * cs + L * sn;
  }
}

// ---------------- fused QKV projection + RoPE (256 blocks x 64 rows).
// 4-WAVE SHAPE (R=4 row-groups x T=3 tiles per wave): LDS read traffic
// = 96(1/R+1/T) = 56KB/step vs 80KB for the old 2x3 8-wave map (-30% reads,
// -21% total LDS traffic) — the K-loop is LDS-BW-bound (112KB/step at
// ~112B/cyc/CU ~= measured 15us; HBM floor is only 10.2us).
// DEPTH-3 x prefetch (3 static slots x 4 float4) + LDS-only barriers (R12).
// Tile sets keep RoPE pairs (c,c+32) lane-local: {0,2,8},{1,3,9},{4,6,10},
// {5,7,11}.
__global__ __launch_bounds__(256) void qkv_rope_kernel(
    const float* __restrict__ x, const u16* __restrict__ wtg,
    u16* __restrict__ qg, u16* __restrict__ kg, u16* __restrict__ vtg) {
  __shared__ __bf16 xbuf[2][64 * 64];
  __shared__ __bf16 wbuf[2][192 * 64];
  const int tid = threadIdx.x;
  const int w = tid >> 6, l = tid & 63;
  const int lr = l & 15, lg = l >> 4;
  const int r0 = blockIdx.x * 64;
  const int b = r0 >> 11, t0 = r0 & 2047;
  constexpr int TM4[4][3] = {{0, 2, 8}, {1, 3, 9}, {4, 6, 10}, {5, 7, 11}};

  f32x4 acc[4][3];
#pragma unroll
  for (int rg = 0; rg < 4; ++rg)
#pragma unroll
    for (int j = 0; j < 3; ++j) acc[rg][j] = (f32x4){0.f, 0.f, 0.f, 0.f};

  // x staging: 2 chunks/thread (rows tid>>3 and tid>>3 + 32), 8 floats each
  const int srow = tid >> 3, sc8 = tid & 7;
  const float* xb0 = x + (size_t)(r0 + srow) * 1024 + sc8 * 8;
  const float* xb1 = xb0 + (size_t)32 * 1024;

  // 3-way static rotation slots, 4 float4 each (all indexing compile-time)
  float4 xA0, xA1, xA2, xA3, xB0, xB1, xB2, xB3, xC0, xC1, xC2, xC3;
  bf16x8 swr[6];

  auto loadW = [&](int k0) {
#pragma unroll
    for (int s = 0; s < 6; ++s) {
      int id = tid + s * 256;
      swr[s] = *(const bf16x8*)(wtg + (size_t)(id >> 3) * 1024 + k0 + (id & 7) * 8);
    }
  };
  auto writeW = [&](int bsel) {
#pragma unroll
    for (int s = 0; s < 6; ++s) {
      int id = tid + s * 256;
      lds_write8(wbuf[bsel], id >> 3, (id & 7) * 8, swr[s]);
    }
  };
  auto loadX = [&](int step, int sel) {
    const float* p0 = xb0 + (size_t)step * 64;
    const float* p1 = xb1 + (size_t)step * 64;
    if (sel == 0) {
      xA0 = *(const float4*)p0; xA1 = *(const float4*)(p0 + 4);
      xA2 = *(const float4*)p1; xA3 = *(const float4*)(p1 + 4);
    } else if (sel == 1) {
      xB0 = *(const float4*)p0; xB1 = *(const float4*)(p0 + 4);
      xB2 = *(const float4*)p1; xB3 = *(const float4*)(p1 + 4);
    } else {
      xC0 = *(const float4*)p0; xC1 = *(const float4*)(p0 + 4);
      xC2 = *(const float4*)p1; xC3 = *(const float4*)(p1 + 4);
    }
  };
  auto writeX = [&](int bsel, int sel) {
    float4 a0, a1, a2, a3;
    if (sel == 0)      { a0 = xA0; a1 = xA1; a2 = xA2; a3 = xA3; }
    else if (sel == 1) { a0 = xB0; a1 = xB1; a2 = xB2; a3 = xB3; }
    else               { a0 = xC0; a1 = xC1; a2 = xC2; a3 = xC3; }
    bf16x8 v;
    v[0] = f2bf(a0.x); v[1] = f2bf(a0.y); v[2] = f2bf(a0.z); v[3] = f2bf(a0.w);
    v[4] = f2bf(a1.x); v[5] = f2bf(a1.y); v[6] = f2bf(a1.z); v[7] = f2bf(a1.w);
    lds_write8(xbuf[bsel], srow, sc8 * 8, v);
    v[0] = f2bf(a2.x); v[1] = f2bf(a2.y); v[2] = f2bf(a2.z); v[3] = f2bf(a2.w);
    v[4] = f2bf(a3.x); v[5] = f2bf(a3.y); v[6] = f2bf(a3.z); v[7] = f2bf(a3.w);
    lds_write8(xbuf[bsel], srow + 32, sc8 * 8, v);
  };

  // prologue: x0 -> slot0 -> LDS0; w0 -> LDS0; x1 -> slot1, x2 -> slot2 fly
  loadX(0, 0);
  loadW(0);
  writeX(0, 0);
  writeW(0);
  loadX(1, 1);
  loadX(2, 2);
  barrier_lds_only();

#pragma unroll
  for (int s = 0; s < 16; ++s) {
    const int cur = s & 1;
    if (s < 13) loadX(s + 3, s % 3);
    if (s < 15) loadW((s + 1) * 64);
#pragma unroll
    for (int kk = 0; kk < 2; ++kk) {
      bf16x8 a0 = lds_read8(xbuf[cur], lr, kk * 32 + lg * 8);
      bf16x8 a1 = lds_read8(xbuf[cur], 16 + lr, kk * 32 + lg * 8);
      bf16x8 a2 = lds_read8(xbuf[cur], 32 + lr, kk * 32 + lg * 8);
      bf16x8 a3 = lds_read8(xbuf[cur], 48 + lr, kk * 32 + lg * 8);
#pragma unroll
      for (int j = 0; j < 3; ++j) {
        bf16x8 bb = lds_read8(wbuf[cur], TM4[w][j] * 16 + lr, kk * 32 + lg * 8);
        acc[0][j] = MFMA(a0, bb, acc[0][j], 0, 0, 0);
        acc[1][j] = MFMA(a1, bb, acc[1][j], 0, 0, 0);
        acc[2][j] = MFMA(a2, bb, acc[2][j], 0, 0, 0);
        acc[3][j] = MFMA(a3, bb, acc[3][j], 0, 0, 0);
      }
    }
    if (s < 15) {
      writeX(cur ^ 1, (s + 1) % 3);
      writeW(cur ^ 1);
      barrier_lds_only();
    }
  }

  // epilogue: RoPE + stores. Phase index i = (w&1)*16 + lr for both q and k.
  const int ph = (w & 1) * 16 + lr;
#pragma unroll
  for (int rg = 0; rg < 4; ++rg) {
    const int rowb = rg * 16 + lg * 4;
    const float t_base = (float)(t0 + rowb);
    rope2(acc[rg][0], acc[rg][1], ph, t_base);
    if (w < 2) {  // q tiles {w, w+2}; fold scale 2^-5
#pragma unroll
      for (int r = 0; r < 4; ++r) {
        size_t rowo = (size_t)(r0 + rowb + r) * 64;
        qg[rowo + ph] = f2bf_bits(acc[rg][0][r] * 0.03125f);
        qg[rowo + 32 + ph] = f2bf_bits(acc[rg][1][r] * 0.03125f);
      }
    } else {  // k tiles {w+2, w+4}
#pragma unroll
      for (int r = 0; r < 4; ++r) {
        size_t rowo = (size_t)(r0 + rowb + r) * 64;
        kg[rowo + ph] = f2bf_bits(acc[rg][0][r]);
        kg[rowo + 32 + ph] = f2bf_bits(acc[rg][1][r]);
      }
    }
    {  // v tile -> transposed vt[b][d][t]
      const int d = (TM4[w][2] - 8) * 16 + lr;
      ushort4 uv;
      uv.x = f2bf_bits(acc[rg][2][0]);
      uv.y = f2bf_bits(acc[rg][2][1]);
      uv.z = f2bf_bits(acc[rg][2][2]);
      uv.w = f2bf_bits(acc[rg][2][3]);
      *(ushort4*)(vtg + (size_t)(b * 64 + d) * 2048 + t0 + rowb) = uv;
    }
  }
}

// ---------------- flash attention split-KV partials (R12-proven depth-1
// staging; gl_lds variant regressed +4.6us R14; depth-2 regressed R9;
// NCH=16 regressed R11; unstaged regressed 20us R13).
// Fixed-shift softmax: P = exp(S - 8), cancels exactly in normalization.
// NO cross-block fences (R4: device-scope __threadfence ~400us on gfx950).
__global__ __launch_bounds__(256) void attn_part_kernel(
    const u16* __restrict__ qg, const u16* __restrict__ kg,
    const u16* __restrict__ vtg, u16* __restrict__ opart,
    float* __restrict__ lpart, float* __restrict__ out, int CT, int NCH) {
  const int idx = blockIdx.x;
  const int b = idx / (32 * NCH);
  const int rem = idx % (32 * NCH);
  const int qt = rem / NCH, ch = rem % NCH;
  const int t0v = ch * CT;
  if (t0v > qt) return;  // uniform early-exit (before any barrier)
  const int t1v = min(qt + 1, t0v + CT);
  const int nv = qt / CT + 1;

  __shared__ __bf16 kbuf[2][64 * 64];
  __shared__ __bf16 vbuf[2][64 * 64];
  __shared__ __bf16 pbuf[4 * 16 * 64];
  const int tid = threadIdx.x;
  const int w = tid >> 6, l = tid & 63;
  const int lr = l & 15, lg = l >> 4;
  const int q0 = qt * 64;
  const float NEG_INF = -__builtin_inff();

  const u16* qrow = qg + (size_t)(b * 2048 + q0 + w * 16 + lr) * 64;
  bf16x8 qf0 = *(const bf16x8*)(qrow + lg * 8);
  bf16x8 qf1 = *(const bf16x8*)(qrow + 32 + lg * 8);

  bf16x8 kr[2], vr[2];
  auto stage_load = [&](int c) {
#pragma unroll
    for (int s = 0; s < 2; ++s) {
      int id = tid + s * 256;
      int row = id >> 3, c8 = id & 7;
      kr[s] = *(const bf16x8*)(kg + (size_t)(b * 2048 + c * 64 + row) * 64 + c8 * 8);
      vr[s] = *(const bf16x8*)(vtg + (size_t)(b * 64 + row) * 2048 + c * 64 + c8 * 8);
    }
  };
  auto stage_write = [&](int bsel) {
#pragma unroll
    for (int s = 0; s < 2; ++s) {
      int id = tid + s * 256;
      int row = id >> 3, c8 = id & 7;
      lds_write8(kbuf[bsel], row, c8 * 8, kr[s]);
      lds_write8(vbuf[bsel], row, c8 * 8, vr[s]);
    }
  };

  f32x4 acc_o[4];
#pragma unroll
  for (int n = 0; n < 4; ++n) acc_o[n] = (f32x4){0.f, 0.f, 0.f, 0.f};
  float l_p[4] = {0.f, 0.f, 0.f, 0.f};  // per-lane partial row sums

  stage_load(t0v);
  stage_write(0);
  __syncthreads();

  for (int c = t0v; c < t1v; ++c) {
    const int cur = (c - t0v) & 1;
    const bool more = (c + 1 < t1v);
    if (more) stage_load(c + 1);  // issue early; hides under QK+exp+PV

    f32x4 s4[4];
#pragma unroll
    for (int nt = 0; nt < 4; ++nt) {
      bf16x8 k0 = lds_read8(kbuf[cur], nt * 16 + lr, lg * 8);
      bf16x8 k1 = lds_read8(kbuf[cur], nt * 16 + lr, 32 + lg * 8);
      f32x4 t = (f32x4){0.f, 0.f, 0.f, 0.f};
      t = MFMA(qf0, k0, t, 0, 0, 0);
      t = MFMA(qf1, k1, t, 0, 0, 0);
      s4[nt] = t;
    }
    if (c == qt) {  // causal mask on diagonal tile
#pragma unroll
      for (int nt = 0; nt < 4; ++nt)
#pragma unroll
        for (int r = 0; r < 4; ++r) {
          int kv = nt * 16 + lr, qq = w * 16 + lg * 4 + r;
          if (kv > qq) s4[nt][r] = NEG_INF;
        }
    }
    // P = exp(S - 8); accumulate per-lane row sums (reduced once after loop)
    __bf16* pw = pbuf + w * (16 * 64);
#pragma unroll
    for (int nt = 0; nt < 4; ++nt)
#pragma unroll
      for (int r = 0; r < 4; ++r) {
        float p = __expf(s4[nt][r] - 8.0f);
        l_p[r] += p;
        pw[swz_off(lg * 4 + r, nt * 16 + lr)] = f2bf(p);
      }
    // wave-internal LDS is in-order: no barrier between P write and read
#pragma unroll
    for (int h = 0; h < 2; ++h) {
      bf16x8 pf = lds_read8(pw, lr, h * 32 + lg * 8);
#pragma unroll
      for (int nt = 0; nt < 4; ++nt) {
        bf16x8 vf = lds_read8(vbuf[cur], nt * 16 + lr, h * 32 + lg * 8);
        acc_o[nt] = MFMA(pf, vf, acc_o[nt], 0, 0, 0);
      }
    }
    if (more) {
      stage_write(cur ^ 1);
      __syncthreads();
    }
  }

  // row sums: reduce l_p across the 16 lr lanes (masks 1,2,4,8 stay in group)
  float lsum[4];
#pragma unroll
  for (int r = 0; r < 4; ++r) {
    float s = l_p[r];
    s += __shfl_xor(s, 1);
    s += __shfl_xor(s, 2);
    s += __shfl_xor(s, 4);
    s += __shfl_xor(s, 8);
    lsum[r] = s;
  }

  if (nv == 1) {  // single chunk: normalize and write out directly
#pragma unroll
    for (int r = 0; r < 4; ++r) {
      float inv = 1.0f / lsum[r];
      size_t rowo = (size_t)(b * 2048 + q0 + w * 16 + lg * 4 + r) * 64;
#pragma unroll
      for (int nt = 0; nt < 4; ++nt)
        out[rowo + nt * 16 + lr] = acc_o[nt][r] * inv;
    }
    return;
  }

  // write unnormalized partial (bf16) + row sums (kernel boundary = coherence)
  const size_t slot = (size_t)(b * 32 + qt) * NCH + ch;
  u16* oslot = opart + slot * 4096;
#pragma unroll
  for (int r = 0; r < 4; ++r) {
    int row = w * 16 + lg * 4 + r;
#pragma unroll
    for (int nt = 0; nt < 4; ++nt)
      oslot[row * 64 + nt * 16 + lr] = f2bf_bits(acc_o[nt][r]);
    if (lr == 0) lpart[slot * 64 + row] = lsum[r];
  }
}

// ---------------- combine partials (unweighted ordered sum; same shift in all
// chunks so weights==1): out = sum_c O'_c / sum_c l_c.
__global__ __launch_bounds__(256) void attn_combine_kernel(
    const u16* __restrict__ opart, const float* __restrict__ lpart,
    float* __restrict__ out, int CT, int NCH) {
  const int bq = blockIdx.x >> 2;
  const int quarter = blockIdx.x & 3;
  const int b = bq >> 5, qt = bq & 31;
  const int nv = qt / CT + 1;
  if (nv == 1) return;  // written directly by attn_part
  const int row = quarter * 16 + (threadIdx.x >> 4);
  const int col = (threadIdx.x & 15) * 4;
  const size_t slot0 = (size_t)(b * 32 + qt) * NCH;

  float denom = 0.f;
  float acc[4] = {0.f, 0.f, 0.f, 0.f};
  for (int c = 0; c < nv; ++c) {
    denom += lpart[(slot0 + c) * 64 + row];
    ushort4 pv = *(const ushort4*)(opart + (slot0 + c) * 4096 + row * 64 + col);
    acc[0] += bf2f(pv.x);
    acc[1] += bf2f(pv.y);
    acc[2] += bf2f(pv.z);
    acc[3] += bf2f(pv.w);
  }
  float inv = 1.0f / denom;
  float4 o;
  o.x = acc[0] * inv; o.y = acc[1] * inv; o.z = acc[2] * inv; o.w = acc[3] * inv;
  *(float4*)(out + ((size_t)(b * 2048 + qt * 64 + row)) * 64 + col) = o;
}

extern "C" void kernel_launch(void* const* d_in, const int* in_sizes, int n_in,
                              void* d_out, int out_size, void* d_ws, size_t ws_size,
                              hipStream_t stream) {
  const float* x = (const float*)d_in[0];
  const float* Wq = (const float*)d_in[1];
  const float* Wk = (const float*)d_in[2];
  const float* Wv = (const float*)d_in[3];
  float* out = (float*)d_out;
  char* ws = (char*)d_ws;
  // ws layout: Wt | q | k | vt | Opart | lpart
  u16* wtg = (u16*)ws;                                  // 393216 B
  u16* qg = (u16*)(ws + 393216);                        // 2 MB
  u16* kg = (u16*)(ws + 393216 + 2097152);              // 2 MB
  u16* vtg = (u16*)(ws + 393216 + 2u * 2097152);        // 2 MB
  const size_t base = 393216 + 3u * 2097152;            // 6,684,672 B
  int NCH = 8;  // proven optimum (R11: NCH=16 +5us; R1: no-split +35us)
  // per slot: 8192 B O' + 256 B l
  while (NCH > 1 && base + (size_t)256 * NCH * 8448 > ws_size) NCH >>= 1;
  const int CT = 32 / NCH;
  u16* opart = (u16*)(ws + base);
  float* lpart = (float*)(ws + base + (size_t)256 * NCH * 8192);

  prep_w_kernel<<<dim3(48), dim3(256), 0, stream>>>(Wq, Wk, Wv, wtg);
  qkv_rope_kernel<<<dim3(256), dim3(256), 0, stream>>>(x, wtg, qg, kg, vtg);
  attn_part_kernel<<<dim3(8 * 32 * NCH), dim3(256), 0, stream>>>(
      qg, kg, vtg, opart, lpart, out, CT, NCH);
  attn_combine_kernel<<<dim3(256 * 4), dim3(256), 0, stream>>>(opart, lpart, out, CT, NCH);
}

// Round 16
// 50.510 us; speedup vs baseline: 1.9063x; 1.0977x over previous
//
#include <hip/hip_runtime.h>

typedef __bf16 bf16x8 __attribute__((ext_vector_type(8)));
typedef float f32x4 __attribute__((ext_vector_type(4)));
typedef unsigned short u16;

#define MFMA __builtin_amdgcn_mfma_f32_16x16x32_bf16

__device__ __forceinline__ u16 f2bf_bits(float f) {
  unsigned u = __builtin_bit_cast(unsigned, f);
  u = (u + 0x7fffu + ((u >> 16) & 1u)) >> 16;
  return (u16)u;
}
__device__ __forceinline__ __bf16 f2bf(float f) {
  u16 b = f2bf_bits(f);
  return __builtin_bit_cast(__bf16, b);
}
__device__ __forceinline__ float bf2f(u16 b) {
  return __builtin_bit_cast(float, (unsigned)b << 16);
}

// Barrier that drains ONLY LDS ops (lgkmcnt), leaving global loads (vmcnt) in
// flight across the barrier (T4). Safe when in-flight loads are lane-private.
__device__ __forceinline__ void barrier_lds_only() {
  asm volatile("s_waitcnt lgkmcnt(0)" ::: "memory");
  __builtin_amdgcn_s_barrier();
}

// LDS tiles: logical [R][64] bf16 rows (128 B). XOR-swizzle 16B chunks with row
// to kill the 128B-stride bank conflict on ds_read_b128 (guide G4).
__device__ __forceinline__ int swz_off(int row, int col) {
  return row * 64 + ((((col >> 3) ^ row) & 7) << 3) + (col & 7);
}
__device__ __forceinline__ bf16x8 lds_read8(const __bf16* buf, int row, int col) {
  return *(const bf16x8*)(buf + (row * 64 + ((((col >> 3) ^ row) & 7) << 3)));
}
__device__ __forceinline__ void lds_write8(__bf16* buf, int row, int col, bf16x8 v) {
  *(bf16x8*)(buf + (row * 64 + ((((col >> 3) ^ row) & 7) << 3))) = v;
}

// ---------------- prep: Wt[192][1024] bf16 via coalesced LDS transpose.
__global__ __launch_bounds__(256) void prep_w_kernel(
    const float* __restrict__ Wq, const float* __restrict__ Wk,
    const float* __restrict__ Wv, u16* __restrict__ wtg) {
  __shared__ float tile[64][65];
  const int tid = threadIdx.x;
  const int kt = blockIdx.x & 15;  // 64 k-rows
  const int ct = blockIdx.x >> 4;  // 0=q, 1=k, 2=v
  const float* W = (ct == 0) ? Wq : ((ct == 1) ? Wk : Wv);
  const int k0 = kt * 64;
#pragma unroll
  for (int i = 0; i < 16; ++i) {
    int row = i * 4 + (tid >> 6), col = tid & 63;
    tile[row][col] = W[(size_t)(k0 + row) * 64 + col];
  }
  __syncthreads();
#pragma unroll
  for (int i = 0; i < 16; ++i) {
    int col = i * 4 + (tid >> 6), krow = tid & 63;
    wtg[(size_t)(ct * 64 + col) * 1024 + k0 + krow] = f2bf_bits(tile[krow][col]);
  }
}

// RoPE a (lo,hi) column pair via native v_sin/v_cos (revolutions + v_fract).
__device__ __forceinline__ void rope2(f32x4& lo, f32x4& hi, int i, float t_base) {
  float f = __expf(-(float)i * 0.28782313662425572f);  // 10000^(-i/32)
  const float inv2pi = 0.15915494309189535f;
#pragma unroll
  for (int r = 0; r < 4; ++r) {
    float rev = (t_base + (float)r) * f * inv2pi;
    rev = __builtin_amdgcn_fractf(rev);
    float sn = __builtin_amdgcn_sinf(rev);
    float cs = __builtin_amdgcn_cosf(rev);
    float L = lo[r], H = hi[r];
    lo[r] = L * cs - H * sn;
    hi[r] = H * cs + L * sn;
  }
}

// ---------------- fused QKV projection + RoPE (256 blocks x 64 rows).
// R12-proven shape (best across R8/R10/R12/R14/R15 A/Bs): 8 waves = 2
// row-groups x 4 col-groups, DEPTH-3 x prefetch (3 static slots), LDS-only
// barriers keep x loads in flight across steps. W (L2-resident) depth-1.
// Tile sets keep RoPE pairs (c,c+32) lane-local.
__global__ __launch_bounds__(512) void qkv_rope_kernel(
    const float* __restrict__ x, const u16* __restrict__ wtg,
    u16* __restrict__ qg, u16* __restrict__ kg, u16* __restrict__ vtg) {
  __shared__ __bf16 xbuf[2][64 * 64];
  __shared__ __bf16 wbuf[2][192 * 64];
  const int tid = threadIdx.x;
  const int w = tid >> 6, l = tid & 63;
  const int wrg = w & 1;
  const int wcg = w >> 1;
  const int lr = l & 15, lg = l >> 4;
  const int r0 = blockIdx.x * 64;
  const int b = r0 >> 11, t0 = r0 & 2047;
  constexpr int TM4[4][3] = {{0, 2, 8}, {1, 3, 9}, {4, 6, 10}, {5, 7, 11}};

  f32x4 acc[2][3];
#pragma unroll
  for (int rg = 0; rg < 2; ++rg)
#pragma unroll
    for (int j = 0; j < 3; ++j) acc[rg][j] = (f32x4){0.f, 0.f, 0.f, 0.f};

  const int srow = tid >> 3, sc8 = tid & 7;
  const float* xbase = x + (size_t)(r0 + srow) * 1024 + sc8 * 8;

  float4 xA0, xA1, xB0, xB1, xC0, xC1;
  bf16x8 swr[3];

  auto loadW = [&](int k0) {
#pragma unroll
    for (int s = 0; s < 3; ++s) {
      int id = tid + s * 512;
      swr[s] = *(const bf16x8*)(wtg + (size_t)(id >> 3) * 1024 + k0 + (id & 7) * 8);
    }
  };
  auto writeW = [&](int bsel) {
#pragma unroll
    for (int s = 0; s < 3; ++s) {
      int id = tid + s * 512;
      lds_write8(wbuf[bsel], id >> 3, (id & 7) * 8, swr[s]);
    }
  };
  auto loadX = [&](int step, int sel) {
    const float* p = xbase + (size_t)step * 64;
    if (sel == 0)      { xA0 = *(const float4*)p; xA1 = *(const float4*)(p + 4); }
    else if (sel == 1) { xB0 = *(const float4*)p; xB1 = *(const float4*)(p + 4); }
    else               { xC0 = *(const float4*)p; xC1 = *(const float4*)(p + 4); }
  };
  auto writeX = [&](int bsel, int sel) {
    float4 a0, a1;
    if (sel == 0)      { a0 = xA0; a1 = xA1; }
    else if (sel == 1) { a0 = xB0; a1 = xB1; }
    else               { a0 = xC0; a1 = xC1; }
    bf16x8 v;
    v[0] = f2bf(a0.x); v[1] = f2bf(a0.y); v[2] = f2bf(a0.z); v[3] = f2bf(a0.w);
    v[4] = f2bf(a1.x); v[5] = f2bf(a1.y); v[6] = f2bf(a1.z); v[7] = f2bf(a1.w);
    lds_write8(xbuf[bsel], srow, sc8 * 8, v);
  };

  loadX(0, 0);
  loadW(0);
  writeX(0, 0);
  writeW(0);
  loadX(1, 1);
  loadX(2, 2);
  barrier_lds_only();

#pragma unroll
  for (int s = 0; s < 16; ++s) {
    const int cur = s & 1;
    if (s < 13) loadX(s + 3, s % 3);
    if (s < 15) loadW((s + 1) * 64);
#pragma unroll
    for (int kk = 0; kk < 2; ++kk) {
      bf16x8 a0 = lds_read8(xbuf[cur], wrg * 32 + lr, kk * 32 + lg * 8);
      bf16x8 a1 = lds_read8(xbuf[cur], wrg * 32 + 16 + lr, kk * 32 + lg * 8);
#pragma unroll
      for (int j = 0; j < 3; ++j) {
        bf16x8 bb = lds_read8(wbuf[cur], TM4[wcg][j] * 16 + lr, kk * 32 + lg * 8);
        acc[0][j] = MFMA(a0, bb, acc[0][j], 0, 0, 0);
        acc[1][j] = MFMA(a1, bb, acc[1][j], 0, 0, 0);
      }
    }
    if (s < 15) {
      writeX(cur ^ 1, (s + 1) % 3);
      writeW(cur ^ 1);
      barrier_lds_only();
    }
  }

  const int ph = (wcg & 1) * 16 + lr;
#pragma unroll
  for (int rg = 0; rg < 2; ++rg) {
    const int rowb = wrg * 32 + rg * 16 + lg * 4;
    const float t_base = (float)(t0 + rowb);
    rope2(acc[rg][0], acc[rg][1], ph, t_base);
    if (wcg < 2) {
#pragma unroll
      for (int r = 0; r < 4; ++r) {
        size_t rowo = (size_t)(r0 + rowb + r) * 64;
        qg[rowo + ph] = f2bf_bits(acc[rg][0][r] * 0.03125f);
        qg[rowo + 32 + ph] = f2bf_bits(acc[rg][1][r] * 0.03125f);
      }
    } else {
#pragma unroll
      for (int r = 0; r < 4; ++r) {
        size_t rowo = (size_t)(r0 + rowb + r) * 64;
        kg[rowo + ph] = f2bf_bits(acc[rg][0][r]);
        kg[rowo + 32 + ph] = f2bf_bits(acc[rg][1][r]);
      }
    }
    {
      const int d = (TM4[wcg][2] - 8) * 16 + lr;
      ushort4 uv;
      uv.x = f2bf_bits(acc[rg][2][0]);
      uv.y = f2bf_bits(acc[rg][2][1]);
      uv.z = f2bf_bits(acc[rg][2][2]);
      uv.w = f2bf_bits(acc[rg][2][3]);
      *(ushort4*)(vtg + (size_t)(b * 64 + d) * 2048 + t0 + rowb) = uv;
    }
  }
}

// ---------------- flash attention split-KV partials (R12-proven depth-1
// staging) + T5 s_setprio around MFMA clusters: attn_part has up to 6
// independent blocks/CU at different chunk phases, the regime where setprio
// paid +4-7% (m191); null only in lockstep single-structure loops (m190).
// Fixed-shift softmax: P = exp(S - 8), cancels exactly in normalization.
// NO cross-block fences (R4: device-scope __threadfence ~400us on gfx950).
__global__ __launch_bounds__(256) void attn_part_kernel(
    const u16* __restrict__ qg, const u16* __restrict__ kg,
    const u16* __restrict__ vtg, u16* __restrict__ opart,
    float* __restrict__ lpart, float* __restrict__ out, int CT, int NCH) {
  const int idx = blockIdx.x;
  const int b = idx / (32 * NCH);
  const int rem = idx % (32 * NCH);
  const int qt = rem / NCH, ch = rem % NCH;
  const int t0v = ch * CT;
  if (t0v > qt) return;  // uniform early-exit (before any barrier)
  const int t1v = min(qt + 1, t0v + CT);
  const int nv = qt / CT + 1;

  __shared__ __bf16 kbuf[2][64 * 64];
  __shared__ __bf16 vbuf[2][64 * 64];
  __shared__ __bf16 pbuf[4 * 16 * 64];
  const int tid = threadIdx.x;
  const int w = tid >> 6, l = tid & 63;
  const int lr = l & 15, lg = l >> 4;
  const int q0 = qt * 64;
  const float NEG_INF = -__builtin_inff();

  const u16* qrow = qg + (size_t)(b * 2048 + q0 + w * 16 + lr) * 64;
  bf16x8 qf0 = *(const bf16x8*)(qrow + lg * 8);
  bf16x8 qf1 = *(const bf16x8*)(qrow + 32 + lg * 8);

  bf16x8 kr[2], vr[2];
  auto stage_load = [&](int c) {
#pragma unroll
    for (int s = 0; s < 2; ++s) {
      int id = tid + s * 256;
      int row = id >> 3, c8 = id & 7;
      kr[s] = *(const bf16x8*)(kg + (size_t)(b * 2048 + c * 64 + row) * 64 + c8 * 8);
      vr[s] = *(const bf16x8*)(vtg + (size_t)(b * 64 + row) * 2048 + c * 64 + c8 * 8);
    }
  };
  auto stage_write = [&](int bsel) {
#pragma unroll
    for (int s = 0; s < 2; ++s) {
      int id = tid + s * 256;
      int row = id >> 3, c8 = id & 7;
      lds_write8(kbuf[bsel], row, c8 * 8, kr[s]);
      lds_write8(vbuf[bsel], row, c8 * 8, vr[s]);
    }
  };

  f32x4 acc_o[4];
#pragma unroll
  for (int n = 0; n < 4; ++n) acc_o[n] = (f32x4){0.f, 0.f, 0.f, 0.f};
  float l_p[4] = {0.f, 0.f, 0.f, 0.f};  // per-lane partial row sums

  stage_load(t0v);
  stage_write(0);
  __syncthreads();

  for (int c = t0v; c < t1v; ++c) {
    const int cur = (c - t0v) & 1;
    const bool more = (c + 1 < t1v);
    if (more) stage_load(c + 1);  // issue early; hides under QK+exp+PV

    f32x4 s4[4];
    __builtin_amdgcn_s_setprio(1);  // favor this wave while in the MFMA pipe
#pragma unroll
    for (int nt = 0; nt < 4; ++nt) {
      bf16x8 k0 = lds_read8(kbuf[cur], nt * 16 + lr, lg * 8);
      bf16x8 k1 = lds_read8(kbuf[cur], nt * 16 + lr, 32 + lg * 8);
      f32x4 t = (f32x4){0.f, 0.f, 0.f, 0.f};
      t = MFMA(qf0, k0, t, 0, 0, 0);
      t = MFMA(qf1, k1, t, 0, 0, 0);
      s4[nt] = t;
    }
    __builtin_amdgcn_s_setprio(0);
    if (c == qt) {  // causal mask on diagonal tile
#pragma unroll
      for (int nt = 0; nt < 4; ++nt)
#pragma unroll
        for (int r = 0; r < 4; ++r) {
          int kv = nt * 16 + lr, qq = w * 16 + lg * 4 + r;
          if (kv > qq) s4[nt][r] = NEG_INF;
        }
    }
    // P = exp(S - 8); accumulate per-lane row sums (reduced once after loop)
    __bf16* pw = pbuf + w * (16 * 64);
#pragma unroll
    for (int nt = 0; nt < 4; ++nt)
#pragma unroll
      for (int r = 0; r < 4; ++r) {
        float p = __expf(s4[nt][r] - 8.0f);
        l_p[r] += p;
        pw[swz_off(lg * 4 + r, nt * 16 + lr)] = f2bf(p);
      }
    // wave-internal LDS is in-order: no barrier between P write and read
    __builtin_amdgcn_s_setprio(1);
#pragma unroll
    for (int h = 0; h < 2; ++h) {
      bf16x8 pf = lds_read8(pw, lr, h * 32 + lg * 8);
#pragma unroll
      for (int nt = 0; nt < 4; ++nt) {
        bf16x8 vf = lds_read8(vbuf[cur], nt * 16 + lr, h * 32 + lg * 8);
        acc_o[nt] = MFMA(pf, vf, acc_o[nt], 0, 0, 0);
      }
    }
    __builtin_amdgcn_s_setprio(0);
    if (more) {
      stage_write(cur ^ 1);
      __syncthreads();
    }
  }

  // row sums: reduce l_p across the 16 lr lanes (masks 1,2,4,8 stay in group)
  float lsum[4];
#pragma unroll
  for (int r = 0; r < 4; ++r) {
    float s = l_p[r];
    s += __shfl_xor(s, 1);
    s += __shfl_xor(s, 2);
    s += __shfl_xor(s, 4);
    s += __shfl_xor(s, 8);
    lsum[r] = s;
  }

  if (nv == 1) {  // single chunk: normalize and write out directly
#pragma unroll
    for (int r = 0; r < 4; ++r) {
      float inv = 1.0f / lsum[r];
      size_t rowo = (size_t)(b * 2048 + q0 + w * 16 + lg * 4 + r) * 64;
#pragma unroll
      for (int nt = 0; nt < 4; ++nt)
        out[rowo + nt * 16 + lr] = acc_o[nt][r] * inv;
    }
    return;
  }

  // write unnormalized partial (bf16) + row sums (kernel boundary = coherence)
  const size_t slot = (size_t)(b * 32 + qt) * NCH + ch;
  u16* oslot = opart + slot * 4096;
#pragma unroll
  for (int r = 0; r < 4; ++r) {
    int row = w * 16 + lg * 4 + r;
#pragma unroll
    for (int nt = 0; nt < 4; ++nt)
      oslot[row * 64 + nt * 16 + lr] = f2bf_bits(acc_o[nt][r]);
    if (lr == 0) lpart[slot * 64 + row] = lsum[r];
  }
}

// ---------------- combine partials (unweighted ordered sum; same shift in all
// chunks so weights==1): out = sum_c O'_c / sum_c l_c.
__global__ __launch_bounds__(256) void attn_combine_kernel(
    const u16* __restrict__ opart, const float* __restrict__ lpart,
    float* __restrict__ out, int CT, int NCH) {
  const int bq = blockIdx.x >> 2;
  const int quarter = blockIdx.x & 3;
  const int b = bq >> 5, qt = bq & 31;
  const int nv = qt / CT + 1;
  if (nv == 1) return;  // written directly by attn_part
  const int row = quarter * 16 + (threadIdx.x >> 4);
  const int col = (threadIdx.x & 15) * 4;
  const size_t slot0 = (size_t)(b * 32 + qt) * NCH;

  float denom = 0.f;
  float acc[4] = {0.f, 0.f, 0.f, 0.f};
  for (int c = 0; c < nv; ++c) {
    denom += lpart[(slot0 + c) * 64 + row];
    ushort4 pv = *(const ushort4*)(opart + (slot0 + c) * 4096 + row * 64 + col);
    acc[0] += bf2f(pv.x);
    acc[1] += bf2f(pv.y);
    acc[2] += bf2f(pv.z);
    acc[3] += bf2f(pv.w);
  }
  float inv = 1.0f / denom;
  float4 o;
  o.x = acc[0] * inv; o.y = acc[1] * inv; o.z = acc[2] * inv; o.w = acc[3] * inv;
  *(float4*)(out + ((size_t)(b * 2048 + qt * 64 + row)) * 64 + col) = o;
}

extern "C" void kernel_launch(void* const* d_in, const int* in_sizes, int n_in,
                              void* d_out, int out_size, void* d_ws, size_t ws_size,
                              hipStream_t stream) {
  const float* x = (const float*)d_in[0];
  const float* Wq = (const float*)d_in[1];
  const float* Wk = (const float*)d_in[2];
  const float* Wv = (const float*)d_in[3];
  float* out = (float*)d_out;
  char* ws = (char*)d_ws;
  // ws layout: Wt | q | k | vt | Opart | lpart
  u16* wtg = (u16*)ws;                                  // 393216 B
  u16* qg = (u16*)(ws + 393216);                        // 2 MB
  u16* kg = (u16*)(ws + 393216 + 2097152);              // 2 MB
  u16* vtg = (u16*)(ws + 393216 + 2u * 2097152);        // 2 MB
  const size_t base = 393216 + 3u * 2097152;            // 6,684,672 B
  int NCH = 8;  // proven optimum (R11: NCH=16 +5us; R1: no-split +35us)
  // per slot: 8192 B O' + 256 B l
  while (NCH > 1 && base + (size_t)256 * NCH * 8448 > ws_size) NCH >>= 1;
  const int CT = 32 / NCH;
  u16* opart = (u16*)(ws + base);
  float* lpart = (float*)(ws + base + (size_t)256 * NCH * 8192);

  prep_w_kernel<<<dim3(48), dim3(256), 0, stream>>>(Wq, Wk, Wv, wtg);
  qkv_rope_kernel<<<dim3(256), dim3(512), 0, stream>>>(x, wtg, qg, kg, vtg);
  attn_part_kernel<<<dim3(8 * 32 * NCH), dim3(256), 0, stream>>>(
      qg, kg, vtg, opart, lpart, out, CT, NCH);
  attn_combine_kernel<<<dim3(256 * 4), dim3(256), 0, stream>>>(opart, lpart, out, CT, NCH);
}

// Round 17
// 46.055 us; speedup vs baseline: 2.0907x; 1.0967x over previous
//
#include <hip/hip_runtime.h>

typedef __bf16 bf16x8 __attribute__((ext_vector_type(8)));
typedef float f32x4 __attribute__((ext_vector_type(4)));
typedef unsigned short u16;

#define MFMA __builtin_amdgcn_mfma_f32_16x16x32_bf16

__device__ __forceinline__ u16 f2bf_bits(float f) {
  unsigned u = __builtin_bit_cast(unsigned, f);
  u = (u + 0x7fffu + ((u >> 16) & 1u)) >> 16;
  return (u16)u;
}
__device__ __forceinline__ __bf16 f2bf(float f) {
  u16 b = f2bf_bits(f);
  return __builtin_bit_cast(__bf16, b);
}
__device__ __forceinline__ float bf2f(u16 b) {
  return __builtin_bit_cast(float, (unsigned)b << 16);
}

// Barrier that drains ONLY LDS ops (lgkmcnt), leaving global loads (vmcnt) in
// flight across the barrier (T4). Safe when in-flight loads are lane-private.
__device__ __forceinline__ void barrier_lds_only() {
  asm volatile("s_waitcnt lgkmcnt(0)" ::: "memory");
  __builtin_amdgcn_s_barrier();
}

// LDS tiles: logical [R][64] bf16 rows (128 B). XOR-swizzle 16B chunks with row
// to kill the 128B-stride bank conflict on ds_read_b128 (guide G4).
__device__ __forceinline__ int swz_off(int row, int col) {
  return row * 64 + ((((col >> 3) ^ row) & 7) << 3) + (col & 7);
}
__device__ __forceinline__ bf16x8 lds_read8(const __bf16* buf, int row, int col) {
  return *(const bf16x8*)(buf + (row * 64 + ((((col >> 3) ^ row) & 7) << 3)));
}
__device__ __forceinline__ void lds_write8(__bf16* buf, int row, int col, bf16x8 v) {
  *(bf16x8*)(buf + (row * 64 + ((((col >> 3) ^ row) & 7) << 3))) = v;
}

// ---------------- prep: Wt[192][1024] bf16 via coalesced LDS transpose.
__global__ __launch_bounds__(256) void prep_w_kernel(
    const float* __restrict__ Wq, const float* __restrict__ Wk,
    const float* __restrict__ Wv, u16* __restrict__ wtg) {
  __shared__ float tile[64][65];
  const int tid = threadIdx.x;
  const int kt = blockIdx.x & 15;  // 64 k-rows
  const int ct = blockIdx.x >> 4;  // 0=q, 1=k, 2=v
  const float* W = (ct == 0) ? Wq : ((ct == 1) ? Wk : Wv);
  const int k0 = kt * 64;
#pragma unroll
  for (int i = 0; i < 16; ++i) {
    int row = i * 4 + (tid >> 6), col = tid & 63;
    tile[row][col] = W[(size_t)(k0 + row) * 64 + col];
  }
  __syncthreads();
#pragma unroll
  for (int i = 0; i < 16; ++i) {
    int col = i * 4 + (tid >> 6), krow = tid & 63;
    wtg[(size_t)(ct * 64 + col) * 1024 + k0 + krow] = f2bf_bits(tile[krow][col]);
  }
}

// RoPE a (lo,hi) column pair via native v_sin/v_cos (revolutions + v_fract).
__device__ __forceinline__ void rope2(f32x4& lo, f32x4& hi, int i, float t_base) {
  float f = __expf(-(float)i * 0.28782313662425572f);  // 10000^(-i/32)
  const float inv2pi = 0.15915494309189535f;
#pragma unroll
  for (int r = 0; r < 4; ++r) {
    float rev = (t_base + (float)r) * f * inv2pi;
    rev = __builtin_amdgcn_fractf(rev);
    float sn = __builtin_amdgcn_sinf(rev);
    float cs = __builtin_amdgcn_cosf(rev);
    float L = lo[r], H = hi[r];
    lo[r] = L * cs - H * sn;
    hi[r] = H * cs + L * sn;
  }
}

// ---------------- fused QKV projection + RoPE (256 blocks x 64 rows).
// R12-proven shape (best across R8/R10/R12/R14/R15 A/Bs): 8 waves = 2
// row-groups x 4 col-groups, DEPTH-3 x prefetch (3 static slots), LDS-only
// barriers keep x loads in flight across steps. W (L2-resident) depth-1.
// Tile sets keep RoPE pairs (c,c+32) lane-local. No setprio here (m190:
// slightly negative in lockstep 1-block/CU loops).
__global__ __launch_bounds__(512) void qkv_rope_kernel(
    const float* __restrict__ x, const u16* __restrict__ wtg,
    u16* __restrict__ qg, u16* __restrict__ kg, u16* __restrict__ vtg) {
  __shared__ __bf16 xbuf[2][64 * 64];
  __shared__ __bf16 wbuf[2][192 * 64];
  const int tid = threadIdx.x;
  const int w = tid >> 6, l = tid & 63;
  const int wrg = w & 1;
  const int wcg = w >> 1;
  const int lr = l & 15, lg = l >> 4;
  const int r0 = blockIdx.x * 64;
  const int b = r0 >> 11, t0 = r0 & 2047;
  constexpr int TM4[4][3] = {{0, 2, 8}, {1, 3, 9}, {4, 6, 10}, {5, 7, 11}};

  f32x4 acc[2][3];
#pragma unroll
  for (int rg = 0; rg < 2; ++rg)
#pragma unroll
    for (int j = 0; j < 3; ++j) acc[rg][j] = (f32x4){0.f, 0.f, 0.f, 0.f};

  const int srow = tid >> 3, sc8 = tid & 7;
  const float* xbase = x + (size_t)(r0 + srow) * 1024 + sc8 * 8;

  float4 xA0, xA1, xB0, xB1, xC0, xC1;
  bf16x8 swr[3];

  auto loadW = [&](int k0) {
#pragma unroll
    for (int s = 0; s < 3; ++s) {
      int id = tid + s * 512;
      swr[s] = *(const bf16x8*)(wtg + (size_t)(id >> 3) * 1024 + k0 + (id & 7) * 8);
    }
  };
  auto writeW = [&](int bsel) {
#pragma unroll
    for (int s = 0; s < 3; ++s) {
      int id = tid + s * 512;
      lds_write8(wbuf[bsel], id >> 3, (id & 7) * 8, swr[s]);
    }
  };
  auto loadX = [&](int step, int sel) {
    const float* p = xbase + (size_t)step * 64;
    if (sel == 0)      { xA0 = *(const float4*)p; xA1 = *(const float4*)(p + 4); }
    else if (sel == 1) { xB0 = *(const float4*)p; xB1 = *(const float4*)(p + 4); }
    else               { xC0 = *(const float4*)p; xC1 = *(const float4*)(p + 4); }
  };
  auto writeX = [&](int bsel, int sel) {
    float4 a0, a1;
    if (sel == 0)      { a0 = xA0; a1 = xA1; }
    else if (sel == 1) { a0 = xB0; a1 = xB1; }
    else               { a0 = xC0; a1 = xC1; }
    bf16x8 v;
    v[0] = f2bf(a0.x); v[1] = f2bf(a0.y); v[2] = f2bf(a0.z); v[3] = f2bf(a0.w);
    v[4] = f2bf(a1.x); v[5] = f2bf(a1.y); v[6] = f2bf(a1.z); v[7] = f2bf(a1.w);
    lds_write8(xbuf[bsel], srow, sc8 * 8, v);
  };

  loadX(0, 0);
  loadW(0);
  writeX(0, 0);
  writeW(0);
  loadX(1, 1);
  loadX(2, 2);
  barrier_lds_only();

#pragma unroll
  for (int s = 0; s < 16; ++s) {
    const int cur = s & 1;
    if (s < 13) loadX(s + 3, s % 3);
    if (s < 15) loadW((s + 1) * 64);
#pragma unroll
    for (int kk = 0; kk < 2; ++kk) {
      bf16x8 a0 = lds_read8(xbuf[cur], wrg * 32 + lr, kk * 32 + lg * 8);
      bf16x8 a1 = lds_read8(xbuf[cur], wrg * 32 + 16 + lr, kk * 32 + lg * 8);
#pragma unroll
      for (int j = 0; j < 3; ++j) {
        bf16x8 bb = lds_read8(wbuf[cur], TM4[wcg][j] * 16 + lr, kk * 32 + lg * 8);
        acc[0][j] = MFMA(a0, bb, acc[0][j], 0, 0, 0);
        acc[1][j] = MFMA(a1, bb, acc[1][j], 0, 0, 0);
      }
    }
    if (s < 15) {
      writeX(cur ^ 1, (s + 1) % 3);
      writeW(cur ^ 1);
      barrier_lds_only();
    }
  }

  const int ph = (wcg & 1) * 16 + lr;
#pragma unroll
  for (int rg = 0; rg < 2; ++rg) {
    const int rowb = wrg * 32 + rg * 16 + lg * 4;
    const float t_base = (float)(t0 + rowb);
    rope2(acc[rg][0], acc[rg][1], ph, t_base);
    if (wcg < 2) {
#pragma unroll
      for (int r = 0; r < 4; ++r) {
        size_t rowo = (size_t)(r0 + rowb + r) * 64;
        qg[rowo + ph] = f2bf_bits(acc[rg][0][r] * 0.03125f);
        qg[rowo + 32 + ph] = f2bf_bits(acc[rg][1][r] * 0.03125f);
      }
    } else {
#pragma unroll
      for (int r = 0; r < 4; ++r) {
        size_t rowo = (size_t)(r0 + rowb + r) * 64;
        kg[rowo + ph] = f2bf_bits(acc[rg][0][r]);
        kg[rowo + 32 + ph] = f2bf_bits(acc[rg][1][r]);
      }
    }
    {
      const int d = (TM4[wcg][2] - 8) * 16 + lr;
      ushort4 uv;
      uv.x = f2bf_bits(acc[rg][2][0]);
      uv.y = f2bf_bits(acc[rg][2][1]);
      uv.z = f2bf_bits(acc[rg][2][2]);
      uv.w = f2bf_bits(acc[rg][2][3]);
      *(ushort4*)(vtg + (size_t)(b * 64 + d) * 2048 + t0 + rowb) = uv;
    }
  }
}

// ---------------- flash attention split-KV partials (R12 staging + R16 T5
// setprio, proven −2.1us) + XCD-aware batch mapping (T1): b = idx & 7 makes
// every block of batch b land on blockIdx ≡ b (mod 8) -> hardware round-robin
// keeps one batch per XCD, and that batch's K+Vt working set (4MB) exactly
// fits the XCD's 4MB L2 — K/V re-reads become L2 hits instead of L3 traffic.
// Fixed-shift softmax: P = exp(S - 8), cancels exactly in normalization.
// NO cross-block fences (R4: device-scope __threadfence ~400us on gfx950).
__global__ __launch_bounds__(256) void attn_part_kernel(
    const u16* __restrict__ qg, const u16* __restrict__ kg,
    const u16* __restrict__ vtg, u16* __restrict__ opart,
    float* __restrict__ lpart, float* __restrict__ out, int CT, int NCH) {
  const int idx = blockIdx.x;
  const int b = idx & 7;        // XCD-aware: batch = idx mod 8 (grid = 8*256)
  const int rem = idx >> 3;
  const int qt = rem / NCH, ch = rem % NCH;
  const int t0v = ch * CT;
  if (t0v > qt) return;  // uniform early-exit (before any barrier)
  const int t1v = min(qt + 1, t0v + CT);
  const int nv = qt / CT + 1;

  __shared__ __bf16 kbuf[2][64 * 64];
  __shared__ __bf16 vbuf[2][64 * 64];
  __shared__ __bf16 pbuf[4 * 16 * 64];
  const int tid = threadIdx.x;
  const int w = tid >> 6, l = tid & 63;
  const int lr = l & 15, lg = l >> 4;
  const int q0 = qt * 64;
  const float NEG_INF = -__builtin_inff();

  const u16* qrow = qg + (size_t)(b * 2048 + q0 + w * 16 + lr) * 64;
  bf16x8 qf0 = *(const bf16x8*)(qrow + lg * 8);
  bf16x8 qf1 = *(const bf16x8*)(qrow + 32 + lg * 8);

  bf16x8 kr[2], vr[2];
  auto stage_load = [&](int c) {
#pragma unroll
    for (int s = 0; s < 2; ++s) {
      int id = tid + s * 256;
      int row = id >> 3, c8 = id & 7;
      kr[s] = *(const bf16x8*)(kg + (size_t)(b * 2048 + c * 64 + row) * 64 + c8 * 8);
      vr[s] = *(const bf16x8*)(vtg + (size_t)(b * 64 + row) * 2048 + c * 64 + c8 * 8);
    }
  };
  auto stage_write = [&](int bsel) {
#pragma unroll
    for (int s = 0; s < 2; ++s) {
      int id = tid + s * 256;
      int row = id >> 3, c8 = id & 7;
      lds_write8(kbuf[bsel], row, c8 * 8, kr[s]);
      lds_write8(vbuf[bsel], row, c8 * 8, vr[s]);
    }
  };

  f32x4 acc_o[4];
#pragma unroll
  for (int n = 0; n < 4; ++n) acc_o[n] = (f32x4){0.f, 0.f, 0.f, 0.f};
  float l_p[4] = {0.f, 0.f, 0.f, 0.f};  // per-lane partial row sums

  stage_load(t0v);
  stage_write(0);
  __syncthreads();

  for (int c = t0v; c < t1v; ++c) {
    const int cur = (c - t0v) & 1;
    const bool more = (c + 1 < t1v);
    if (more) stage_load(c + 1);  // issue early; hides under QK+exp+PV

    f32x4 s4[4];
    __builtin_amdgcn_s_setprio(1);  // favor this wave while in the MFMA pipe
#pragma unroll
    for (int nt = 0; nt < 4; ++nt) {
      bf16x8 k0 = lds_read8(kbuf[cur], nt * 16 + lr, lg * 8);
      bf16x8 k1 = lds_read8(kbuf[cur], nt * 16 + lr, 32 + lg * 8);
      f32x4 t = (f32x4){0.f, 0.f, 0.f, 0.f};
      t = MFMA(qf0, k0, t, 0, 0, 0);
      t = MFMA(qf1, k1, t, 0, 0, 0);
      s4[nt] = t;
    }
    __builtin_amdgcn_s_setprio(0);
    if (c == qt) {  // causal mask on diagonal tile
#pragma unroll
      for (int nt = 0; nt < 4; ++nt)
#pragma unroll
        for (int r = 0; r < 4; ++r) {
          int kv = nt * 16 + lr, qq = w * 16 + lg * 4 + r;
          if (kv > qq) s4[nt][r] = NEG_INF;
        }
    }
    // P = exp(S - 8); accumulate per-lane row sums (reduced once after loop)
    __bf16* pw = pbuf + w * (16 * 64);
#pragma unroll
    for (int nt = 0; nt < 4; ++nt)
#pragma unroll
      for (int r = 0; r < 4; ++r) {
        float p = __expf(s4[nt][r] - 8.0f);
        l_p[r] += p;
        pw[swz_off(lg * 4 + r, nt * 16 + lr)] = f2bf(p);
      }
    // wave-internal LDS is in-order: no barrier between P write and read
    __builtin_amdgcn_s_setprio(1);
#pragma unroll
    for (int h = 0; h < 2; ++h) {
      bf16x8 pf = lds_read8(pw, lr, h * 32 + lg * 8);
#pragma unroll
      for (int nt = 0; nt < 4; ++nt) {
        bf16x8 vf = lds_read8(vbuf[cur], nt * 16 + lr, h * 32 + lg * 8);
        acc_o[nt] = MFMA(pf, vf, acc_o[nt], 0, 0, 0);
      }
    }
    __builtin_amdgcn_s_setprio(0);
    if (more) {
      stage_write(cur ^ 1);
      __syncthreads();
    }
  }

  // row sums: reduce l_p across the 16 lr lanes (masks 1,2,4,8 stay in group)
  float lsum[4];
#pragma unroll
  for (int r = 0; r < 4; ++r) {
    float s = l_p[r];
    s += __shfl_xor(s, 1);
    s += __shfl_xor(s, 2);
    s += __shfl_xor(s, 4);
    s += __shfl_xor(s, 8);
    lsum[r] = s;
  }

  if (nv == 1) {  // single chunk: normalize and write out directly
#pragma unroll
    for (int r = 0; r < 4; ++r) {
      float inv = 1.0f / lsum[r];
      size_t rowo = (size_t)(b * 2048 + q0 + w * 16 + lg * 4 + r) * 64;
#pragma unroll
      for (int nt = 0; nt < 4; ++nt)
        out[rowo + nt * 16 + lr] = acc_o[nt][r] * inv;
    }
    return;
  }

  // write unnormalized partial (bf16) + row sums (kernel boundary = coherence)
  const size_t slot = (size_t)(b * 32 + qt) * NCH + ch;
  u16* oslot = opart + slot * 4096;
#pragma unroll
  for (int r = 0; r < 4; ++r) {
    int row = w * 16 + lg * 4 + r;
#pragma unroll
    for (int nt = 0; nt < 4; ++nt)
      oslot[row * 64 + nt * 16 + lr] = f2bf_bits(acc_o[nt][r]);
    if (lr == 0) lpart[slot * 64 + row] = lsum[r];
  }
}

// ---------------- combine partials (unweighted ordered sum; same shift in all
// chunks so weights==1): out = sum_c O'_c / sum_c l_c.
__global__ __launch_bounds__(256) void attn_combine_kernel(
    const u16* __restrict__ opart, const float* __restrict__ lpart,
    float* __restrict__ out, int CT, int NCH) {
  const int bq = blockIdx.x >> 2;
  const int quarter = blockIdx.x & 3;
  const int b = bq >> 5, qt = bq & 31;
  const int nv = qt / CT + 1;
  if (nv == 1) return;  // written directly by attn_part
  const int row = quarter * 16 + (threadIdx.x >> 4);
  const int col = (threadIdx.x & 15) * 4;
  const size_t slot0 = (size_t)(b * 32 + qt) * NCH;

  float denom = 0.f;
  float acc[4] = {0.f, 0.f, 0.f, 0.f};
  for (int c = 0; c < nv; ++c) {
    denom += lpart[(slot0 + c) * 64 + row];
    ushort4 pv = *(const ushort4*)(opart + (slot0 + c) * 4096 + row * 64 + col);
    acc[0] += bf2f(pv.x);
    acc[1] += bf2f(pv.y);
    acc[2] += bf2f(pv.z);
    acc[3] += bf2f(pv.w);
  }
  float inv = 1.0f / denom;
  float4 o;
  o.x = acc[0] * inv; o.y = acc[1] * inv; o.z = acc[2] * inv; o.w = acc[3] * inv;
  *(float4*)(out + ((size_t)(b * 2048 + qt * 64 + row)) * 64 + col) = o;
}

extern "C" void kernel_launch(void* const* d_in, const int* in_sizes, int n_in,
                              void* d_out, int out_size, void* d_ws, size_t ws_size,
                              hipStream_t stream) {
  const float* x = (const float*)d_in[0];
  const float* Wq = (const float*)d_in[1];
  const float* Wk = (const float*)d_in[2];
  const float* Wv = (const float*)d_in[3];
  float* out = (float*)d_out;
  char* ws = (char*)d_ws;
  // ws layout: Wt | q | k | vt | Opart | lpart
  u16* wtg = (u16*)ws;                                  // 393216 B
  u16* qg = (u16*)(ws + 393216);                        // 2 MB
  u16* kg = (u16*)(ws + 393216 + 2097152);              // 2 MB
  u16* vtg = (u16*)(ws + 393216 + 2u * 2097152);        // 2 MB
  const size_t base = 393216 + 3u * 2097152;            // 6,684,672 B
  int NCH = 8;  // proven optimum (R11: NCH=16 +5us; R1: no-split +35us)
  // per slot: 8192 B O' + 256 B l
  while (NCH > 1 && base + (size_t)256 * NCH * 8448 > ws_size) NCH >>= 1;
  const int CT = 32 / NCH;
  u16* opart = (u16*)(ws + base);
  float* lpart = (float*)(ws + base + (size_t)256 * NCH * 8192);

  prep_w_kernel<<<dim3(48), dim3(256), 0, stream>>>(Wq, Wk, Wv, wtg);
  qkv_rope_kernel<<<dim3(256), dim3(512), 0, stream>>>(x, wtg, qg, kg, vtg);
  attn_part_kernel<<<dim3(8 * 32 * NCH), dim3(256), 0, stream>>>(
      qg, kg, vtg, opart, lpart, out, CT, NCH);
  attn_combine_kernel<<<dim3(256 * 4), dim3(256), 0, stream>>>(opart, lpart, out, CT, NCH);
}